// Round 7
// baseline (359.926 us; speedup 1.0000x reference)
//
#include <hip/hip_runtime.h>
#include <math.h>

typedef _Float16 f16;
typedef _Float16 f16x2 __attribute__((ext_vector_type(2)));
typedef _Float16 f16x8 __attribute__((ext_vector_type(8)));
typedef float f32x4 __attribute__((ext_vector_type(4)));

static constexpr int Mrows = 1568;   // 32*49
static constexpr int NPAIR = 76832;  // 32*49*49
static constexpr float SCALEC = 0.125f;
#define EPSV 1e-5f

// ---------- helpers ----------
__device__ inline float wsum(float v) {
#pragma unroll
  for (int m = 32; m >= 1; m >>= 1) v += __shfl_xor(v, m, 64);
  return v;
}
__device__ inline float wmax(float v) {
#pragma unroll
  for (int m = 32; m >= 1; m >>= 1) v = fmaxf(v, __shfl_xor(v, m, 64));
  return v;
}
__device__ inline void gld16(const void* g, void* l) {
  __builtin_amdgcn_global_load_lds((const __attribute__((address_space(1))) void*)g,
                                   (__attribute__((address_space(3))) void*)l, 16, 0, 0);
}
__device__ inline f16x2 H2(unsigned u) { return __builtin_bit_cast(f16x2, u); }
__device__ inline unsigned U32(f16x2 h) { return __builtin_bit_cast(unsigned, h); }
__device__ inline f16x2 pk2(float a, float b) {
  return __builtin_bit_cast(f16x2, __builtin_amdgcn_cvt_pkrtz(a, b));
}
__device__ inline float qsum(float v) {
  v += __shfl_xor(v, 1, 64);
  v += __shfl_xor(v, 2, 64);
  return v;
}

// ---------- prep: zero h | build padded Qp (f16) | convW -> Wtb [o][t*512+c] f16 ----------
__global__ __launch_bounds__(256) void prep(const float* __restrict__ queries,
                                            const float* __restrict__ convW,
                                            float* __restrict__ h,
                                            f16* __restrict__ Qp,
                                            f16* __restrict__ Wtb) {
  int bx = blockIdx.x;
  int tid = threadIdx.x;
  if (bx < 784) {
    ((float4*)h)[bx * 256 + tid] = make_float4(0.f, 0.f, 0.f, 0.f);
  } else if (bx < 784 + 5184) {
    int idx = (bx - 784) * 256 + tid;
    int c = idx & 511;
    int iijj = (idx >> 9) % 81;
    int b = idx / (81 * 512);
    int ii = iijj / 9, jj = iijj % 9;
    float v = 0.f;
    if (ii >= 1 && ii <= 7 && jj >= 1 && jj <= 7)
      v = queries[(((size_t)(b * 49 + (ii - 1) * 7 + (jj - 1))) << 9) + c];
    Qp[idx] = (f16)v;
  } else {
    int idx = (bx - 5968) * 256 + tid;
    int o = idx >> 9, c = idx & 511;
    const float* s = convW + (size_t)o * 4608 + c * 9;
    f16* d = Wtb + (size_t)o * 4608 + c;
#pragma unroll
    for (int t = 0; t < 9; t++) d[t * 512] = (f16)s[t];
  }
}

// ---------- small precomputes (wave-parallel): crel[14], wrg[512], cconst ----------
__global__ __launch_bounds__(256) void smalls_kernel(
    const float* __restrict__ Wproj, const float* __restrict__ Wgate,
    const float* __restrict__ rel_embed, const float* __restrict__ bproj,
    const float* __restrict__ br2, const float* __restrict__ bgate,
    const float* __restrict__ Wr2, float* __restrict__ crel,
    float* __restrict__ wrg, float* __restrict__ cconst) {
  int tid = threadIdx.x;
  int wv = tid >> 6, lane = tid & 63;
  if (blockIdx.x == 0) {
    __shared__ float pg[64];
    for (int o = wv; o < 64; o += 4) {
      float s = 0.f;
      for (int d = lane; d < 512; d += 64) s += Wproj[o * 512 + d] * Wgate[d];
      s = wsum(s);
      if (lane == 0) pg[o] = s;
    }
    if (wv == 3) {
      float s = 0.f;
      for (int d = lane; d < 512; d += 64) s += (bproj[d] + br2[d]) * Wgate[d];
      s = wsum(s);
      if (lane == 0) cconst[0] = s + bgate[0];
    }
    __syncthreads();
    if (tid < 14) {
      float s = 0.f;
      for (int dk = 0; dk < 64; dk++) s += rel_embed[tid * 64 + dk] * pg[dk];
      crel[tid] = s;
    }
  } else {
    int d = (blockIdx.x - 1) * 4 + wv;  // 128 blocks * 4 waves = 512
    float s = 0.f;
    for (int d2 = lane; d2 < 512; d2 += 64) s += Wr2[(size_t)d * 512 + d2] * Wgate[d2];
    s = wsum(s);
    if (lane == 0) wrg[d] = s;
  }
}

// ---------- tiled transpose+convert (weights): dst[n][k] = (f16)src[k][n], K=512 ----------
struct TJobs { const float* src[8]; f16* dst[8]; int cols[8]; };
__global__ __launch_bounds__(256) void transpose_w(TJobs tj) {
  int z = blockIdx.z;
  int cols = tj.cols[z];
  int n0 = blockIdx.x * 32;
  if (n0 >= cols) return;
  int k0 = blockIdx.y * 32;
  const float* src = tj.src[z];
  f16* dst = tj.dst[z];
  __shared__ float tile[32][33];
  int tid = threadIdx.x;
  int c = tid & 31, r0 = tid >> 5;
#pragma unroll
  for (int i = 0; i < 4; i++) {
    int r = r0 + i * 8;
    tile[r][c] = src[(size_t)(k0 + r) * cols + n0 + c];
  }
  __syncthreads();
#pragma unroll
  for (int i = 0; i < 4; i++) {
    int r = r0 + i * 8;
    dst[(size_t)(n0 + r) * 512 + k0 + c] = (f16)tile[c][r];
  }
}

// ---------- activation transpose to packed f16-pair layout: dst[dpair][row] ----------
struct T2Jobs { const float* src[4]; unsigned* dst[4]; int C[4]; };
__global__ __launch_bounds__(256) void t2h(T2Jobs tj) {
  int z = blockIdx.z;
  int C = tj.C[z];
  int c0 = blockIdx.x * 32;
  if (c0 >= C) return;
  int r0 = blockIdx.y * 32;
  const float* src = tj.src[z];
  unsigned* dst = tj.dst[z];
  __shared__ float tile[32][33];  // [col][row]
  int t = threadIdx.x;
  int cc = t & 31, rr = t >> 5;
#pragma unroll
  for (int i = 0; i < 4; i++)
    tile[cc][rr + i * 8] = src[(size_t)(r0 + rr + i * 8) * C + c0 + cc];
  __syncthreads();
  int r = t & 31, cp = t >> 5;
#pragma unroll
  for (int i = 0; i < 2; i++) {
    int c = cp + i * 8;
    f16x2 p = pk2(tile[2 * c][r], tile[2 * c + 1][r]);
    dst[(size_t)((c0 >> 1) + c) * 1568 + r0 + r] = U32(p);
  }
}

// ---------- per-row sums: S[row]=Σx, SS[row]=Σx² for Cq,Ck (256) / Rq,Rk (512) ----------
struct RSJobs { const float* src[4]; int w[4]; };
__global__ __launch_bounds__(256) void row_sums(RSJobs rj, float* __restrict__ Ssum,
                                                float* __restrict__ SSsum) {
  int j = blockIdx.y;
  int w = rj.w[j];
  const float* src = rj.src[j];
  int row = blockIdx.x * 4 + (threadIdx.x >> 6);
  int lane = threadIdx.x & 63;
  float s = 0.f, ss = 0.f;
  for (int c = lane; c < w; c += 64) {
    float v = src[(size_t)row * w + c];
    s += v;
    ss += v * v;
  }
  s = wsum(s);
  ss = wsum(ss);
  if (lane == 0) {
    Ssum[j * 1568 + row] = s;
    SSsum[j * 1568 + row] = ss;
  }
}

// ---------- batched Gram via MFMA: dot[b][q][k] = 2 * (Q_row_q · K_row_k) ----------
// blockIdx.x: 0..63 -> z = idx>>5 (0: C K=256, 1: R K=512), b = idx&31
__global__ __launch_bounds__(256) void gram_mfma(const f16* __restrict__ Cqh,
                                                 const f16* __restrict__ Ckh,
                                                 const f16* __restrict__ Rqh,
                                                 const f16* __restrict__ Rkh,
                                                 float* __restrict__ dotC,
                                                 float* __restrict__ dotR) {
  int idx = blockIdx.x;
  int z = idx >> 5, b = idx & 31;
  int K = z ? 512 : 256;
  const f16* A = (z ? Rqh : Cqh) + (size_t)b * 49 * K;
  const f16* BT = (z ? Rkh : Ckh) + (size_t)b * 49 * K;
  float* out = (z ? dotR : dotC) + (size_t)b * 2401;
  __shared__ f16 As2[2048];
  __shared__ f16 Bs2[2048];
  int tid = threadIdx.x, lane = tid & 63, wv = tid >> 6;
  int kq = (tid >> 4) & 3, mm = tid & 15;
  int rowA = wv * 16 + mm;
  if (rowA > 48) rowA = 48;
  const f16* aSrc = A + (size_t)rowA * K + kq * 8;
  const f16* bSrc = BT + (size_t)rowA * K + kq * 8;
  f16* aDst = &As2[wv * 512];
  f16* bDst = &Bs2[wv * 512];
  f32x4 acc[4];
#pragma unroll
  for (int i = 0; i < 4; i++) acc[i] = (f32x4){0.f, 0.f, 0.f, 0.f};
  int steps = K >> 5;
  for (int s = 0; s < steps; s++) {
    gld16(aSrc + s * 32, aDst);
    gld16(bSrc + s * 32, bDst);
    __syncthreads();
    f16x8 a = *(const f16x8*)&As2[(wv << 9) + (lane << 3)];
#pragma unroll
    for (int nb = 0; nb < 4; nb++) {
      f16x8 bf = *(const f16x8*)&Bs2[(nb << 9) + (lane << 3)];
      acc[nb] = __builtin_amdgcn_mfma_f32_16x16x32_f16(a, bf, acc[nb], 0, 0, 0);
    }
    __syncthreads();
  }
  int r0 = wv * 16 + ((lane >> 4) << 2);
  int cw = lane & 15;
#pragma unroll
  for (int nb = 0; nb < 4; nb++) {
    int col = nb * 16 + cw;
#pragma unroll
    for (int r = 0; r < 4; r++) {
      int row = r0 + r;
      if (row < 49 && col < 49) out[row * 49 + col] = 2.f * acc[nb][r];
    }
  }
}

// ---------- conv as implicit-im2col MFMA GEMM, split-K=8, atomicAdd into h ----------
__global__ __launch_bounds__(256) void conv_mfma(const f16* __restrict__ Qp,
                                                 const f16* __restrict__ Wtb,
                                                 float* __restrict__ h) {
  __shared__ f16 As2[2048];
  __shared__ f16 Bs2[2048];
  int tid = threadIdx.x;
  int n0 = blockIdx.x * 64;
  int m0 = blockIdx.y * 64;
  int kb = blockIdx.z * 576;
  int lane = tid & 63, wv = tid >> 6;
  int kq = (tid >> 4) & 3, mm = tid & 15;
  int rowA = m0 + wv * 16 + mm;
  if (rowA > Mrows - 1) rowA = Mrows - 1;
  int b = rowA / 49, p = rowA % 49;
  int pi = p / 7, pj = p % 7;
  const f16* qbase = Qp + (size_t)b * 81 * 512 + kq * 8;
  int rowB = n0 + wv * 16 + mm;
  const f16* bSrc = Wtb + (size_t)rowB * 4608 + kq * 8 + kb;
  f16* aDst = &As2[wv * 512];
  f16* bDst = &Bs2[wv * 512];
  f32x4 acc[4];
#pragma unroll
  for (int i = 0; i < 4; i++) acc[i] = (f32x4){0.f, 0.f, 0.f, 0.f};
  for (int s = 0; s < 18; s++) {
    int k0 = kb + s * 32;
    int t = k0 >> 9, c0 = k0 & 511;
    int ti = t / 3, tj = t - ti * 3;
    const f16* aSrc = qbase + (size_t)((pi + ti) * 9 + (pj + tj)) * 512 + c0;
    gld16(aSrc, aDst);
    gld16(bSrc + s * 32, bDst);
    __syncthreads();
    f16x8 a = *(const f16x8*)&As2[(wv << 9) + (lane << 3)];
#pragma unroll
    for (int nb = 0; nb < 4; nb++) {
      f16x8 bf = *(const f16x8*)&Bs2[(nb << 9) + (lane << 3)];
      acc[nb] = __builtin_amdgcn_mfma_f32_16x16x32_f16(a, bf, acc[nb], 0, 0, 0);
    }
    __syncthreads();
  }
  int r0 = m0 + wv * 16 + ((lane >> 4) << 2);
  int cw = lane & 15;
#pragma unroll
  for (int nb = 0; nb < 4; nb++) {
    int col = n0 + nb * 16 + cw;
#pragma unroll
    for (int r = 0; r < 4; r++) {
      int row = r0 + r;
      if (row < Mrows) atomicAdd(&h[(size_t)row * 512 + col], acc[nb][r]);
    }
  }
}

// ---------- BatchNorm stats per channel ----------
__global__ __launch_bounds__(256) void bn_stats(const float* __restrict__ h,
                                                float* __restrict__ mu,
                                                float* __restrict__ rsg) {
  int c = blockIdx.x;
  int tid = threadIdx.x;
  float s = 0.f, ss = 0.f;
  for (int r = tid; r < Mrows; r += 256) {
    float v = h[(size_t)r * 512 + c];
    s += v;
    ss += v * v;
  }
  s = wsum(s);
  ss = wsum(ss);
  __shared__ float r1[4], r2[4];
  int wave = tid >> 6, lane = tid & 63;
  if (lane == 0) { r1[wave] = s; r2[wave] = ss; }
  __syncthreads();
  if (tid == 0) {
    float S = r1[0] + r1[1] + r1[2] + r1[3];
    float SS = r2[0] + r2[1] + r2[2] + r2[3];
    float m = S / (float)Mrows;
    float var = SS / (float)Mrows - m * m;
    mu[c] = m;
    rsg[c] = rsqrtf(var + EPSV);
  }
}

// ---------- xs = relu(bn(h)); eq/ek/ev (f16) ----------
__global__ __launch_bounds__(256) void fuse_xs(
    const float* __restrict__ h, const float* __restrict__ mu,
    const float* __restrict__ rsg, const float* __restrict__ Q,
    const float* __restrict__ Kin, const float* __restrict__ Vin,
    f16* __restrict__ eqh, f16* __restrict__ ekh, f16* __restrict__ evh) {
  int i = blockIdx.x * 256 + threadIdx.x;
  int c = i & 511;
  float xs = fmaxf((h[i] - mu[c]) * rsg[c], 0.f);
  eqh[i] = (f16)(xs + Q[i]);
  ekh[i] = (f16)(xs + Kin[i]);
  evh[i] = (f16)(xs + Vin[i]);
}

// ---------- generic MFMA GEMM: C[z] = A[z](f16,[M][512]) @ BT[z]^T (+bias) ----------
// fp32 out; optional f16 row-major copy (for Gram inputs)
struct MJobs {
  const f16* A[7]; const f16* BT[7]; const float* bias[7];
  float* C[7]; f16* Ch[7]; int N[7];
};
__global__ __launch_bounds__(256) void gemm_mf(MJobs jb) {
  int z = blockIdx.z;
  int N = jb.N[z];
  int n0 = blockIdx.x * 64;
  if (n0 >= N) return;
  int m0 = blockIdx.y * 64;
  const f16* A = jb.A[z];
  const f16* BT = jb.BT[z];
  __shared__ f16 As2[2048];
  __shared__ f16 Bs2[2048];
  int tid = threadIdx.x, lane = tid & 63, wv = tid >> 6;
  int kq = (tid >> 4) & 3, mm = tid & 15;
  int rowA = m0 + wv * 16 + mm;
  if (rowA > Mrows - 1) rowA = Mrows - 1;
  const f16* aSrc = A + (size_t)rowA * 512 + kq * 8;
  int rowB = n0 + wv * 16 + mm;
  const f16* bSrc = BT + (size_t)rowB * 512 + kq * 8;
  f16* aDst = &As2[wv * 512];
  f16* bDst = &Bs2[wv * 512];
  f32x4 acc[4];
#pragma unroll
  for (int i = 0; i < 4; i++) acc[i] = (f32x4){0.f, 0.f, 0.f, 0.f};
  for (int s = 0; s < 16; s++) {
    gld16(aSrc + s * 32, aDst);
    gld16(bSrc + s * 32, bDst);
    __syncthreads();
    f16x8 a = *(const f16x8*)&As2[(wv << 9) + (lane << 3)];
#pragma unroll
    for (int nb = 0; nb < 4; nb++) {
      f16x8 bf = *(const f16x8*)&Bs2[(nb << 9) + (lane << 3)];
      acc[nb] = __builtin_amdgcn_mfma_f32_16x16x32_f16(a, bf, acc[nb], 0, 0, 0);
    }
    __syncthreads();
  }
  const float* bias = jb.bias[z];
  float* C = jb.C[z];
  f16* Ch = jb.Ch[z];
  int r0 = m0 + wv * 16 + ((lane >> 4) << 2);
  int cw = lane & 15;
#pragma unroll
  for (int nb = 0; nb < 4; nb++) {
    int col = n0 + nb * 16 + cw;
    float bv = bias ? bias[col] : 0.f;
#pragma unroll
    for (int r = 0; r < 4; r++) {
      int row = r0 + r;
      if (row < Mrows) {
        float v = acc[nb][r] + bv;
        C[(size_t)row * N + col] = v;
        if (Ch) Ch[(size_t)row * N + col] = (f16)v;
      }
    }
  }
}

// ---------- pair gate: quad-per-pair, SINGLE pass (analytic LN stats) ----------
__global__ __launch_bounds__(256) void pair_gate(
    const unsigned* __restrict__ CqT, const unsigned* __restrict__ CkT,
    const unsigned* __restrict__ RqT, const unsigned* __restrict__ RkT,
    const float* __restrict__ Wc2, const float* __restrict__ bc2,
    const float* __restrict__ gc, const float* __restrict__ bcln,
    const float* __restrict__ gr, const float* __restrict__ brln,
    const float* __restrict__ crel, const float* __restrict__ wrg,
    const float* __restrict__ cconstp, const float* __restrict__ Ssum,
    const float* __restrict__ SSsum, const float* __restrict__ dotC,
    const float* __restrict__ dotR, float* __restrict__ gfac) {
  __shared__ uint4 sTC[512];   // [dd][4]: {gc2,bcln2,W2 r0..13 pairs}
  __shared__ uint4 sTR[256];   // [dd]: {gr2, brln2, wrg2, 0}
  __shared__ float scl[14], sb2[14];
  int tid = threadIdx.x;
  if (tid < 128) {
    int dd = tid;
    unsigned w[16];
    w[0] = U32(pk2(gc[2 * dd], gc[2 * dd + 1]));
    w[1] = U32(pk2(bcln[2 * dd], bcln[2 * dd + 1]));
#pragma unroll
    for (int r = 0; r < 14; r++)
      w[2 + r] = U32(pk2(Wc2[(2 * dd) * 14 + r], Wc2[(2 * dd + 1) * 14 + r]));
#pragma unroll
    for (int j = 0; j < 4; j++)
      sTC[dd * 4 + j] = make_uint4(w[4 * j], w[4 * j + 1], w[4 * j + 2], w[4 * j + 3]);
  }
  {
    int dd = tid;
    sTR[dd] = make_uint4(U32(pk2(gr[2 * dd], gr[2 * dd + 1])),
                         U32(pk2(brln[2 * dd], brln[2 * dd + 1])),
                         U32(pk2(wrg[2 * dd], wrg[2 * dd + 1])), 0u);
  }
  if (tid < 14) { scl[tid] = crel[tid]; sb2[tid] = bc2[tid]; }
  __syncthreads();

  int gidx = blockIdx.x * 256 + tid;
  int pid = gidx >> 2;
  int sub = gidx & 3;
  bool valid = pid < NPAIR;
  int pc = valid ? pid : NPAIR - 1;
  int b = pc / 2401;
  int r2 = pc % 2401;
  int q = r2 / 49, k = r2 % 49;
  int rowq = b * 49 + q, rowk = b * 49 + k;
  const f16x2 zero2 = {(f16)0.f, (f16)0.f};

  float s1;
  {
    // analytic classifier LN stats
    float sC = Ssum[rowq] + Ssum[1568 + rowk];
    float ssC = SSsum[rowq] + SSsum[1568 + rowk] + dotC[pc];
    float mC = sC * (1.f / 256.f);
    float var = ssC * (1.f / 256.f) - mC * mC;
    float rsC = rsqrtf(var + EPSV);
    f16x2 nm2 = pk2(-mC, -mC);
    f16x2 rs2 = pk2(rsC, rsC);

    float lg[14];
#pragma unroll
    for (int r = 0; r < 14; r++) lg[r] = 0.f;
    const unsigned* cq = CqT + (size_t)sub * 1568 + rowq;
    const unsigned* ck = CkT + (size_t)sub * 1568 + rowk;
#pragma unroll
    for (int j = 0; j < 32; j++) {
      int dd = 4 * j + sub;
      uint4 t0 = sTC[dd * 4 + 0];
      uint4 t1 = sTC[dd * 4 + 1];
      uint4 t2 = sTC[dd * 4 + 2];
      uint4 t3 = sTC[dd * 4 + 3];
      f16x2 z2 = H2(cq[(size_t)j * 4 * 1568]) + H2(ck[(size_t)j * 4 * 1568]);
      f16x2 u2 = (z2 + nm2) * rs2;
      f16x2 h2 = __builtin_elementwise_max(u2 * H2(t0.x) + H2(t0.y), zero2);
      lg[0] = __builtin_amdgcn_fdot2(h2, H2(t0.z), lg[0], false);
      lg[1] = __builtin_amdgcn_fdot2(h2, H2(t0.w), lg[1], false);
      lg[2] = __builtin_amdgcn_fdot2(h2, H2(t1.x), lg[2], false);
      lg[3] = __builtin_amdgcn_fdot2(h2, H2(t1.y), lg[3], false);
      lg[4] = __builtin_amdgcn_fdot2(h2, H2(t1.z), lg[4], false);
      lg[5] = __builtin_amdgcn_fdot2(h2, H2(t1.w), lg[5], false);
      lg[6] = __builtin_amdgcn_fdot2(h2, H2(t2.x), lg[6], false);
      lg[7] = __builtin_amdgcn_fdot2(h2, H2(t2.y), lg[7], false);
      lg[8] = __builtin_amdgcn_fdot2(h2, H2(t2.z), lg[8], false);
      lg[9] = __builtin_amdgcn_fdot2(h2, H2(t2.w), lg[9], false);
      lg[10] = __builtin_amdgcn_fdot2(h2, H2(t3.x), lg[10], false);
      lg[11] = __builtin_amdgcn_fdot2(h2, H2(t3.y), lg[11], false);
      lg[12] = __builtin_amdgcn_fdot2(h2, H2(t3.z), lg[12], false);
      lg[13] = __builtin_amdgcn_fdot2(h2, H2(t3.w), lg[13], false);
    }
#pragma unroll
    for (int r = 0; r < 14; r++) lg[r] = qsum(lg[r]) + sb2[r];

    float mx = lg[0];
#pragma unroll
    for (int r = 1; r < 14; r++) mx = fmaxf(mx, lg[r]);
    float se = 0.f, sc = 0.f;
#pragma unroll
    for (int r = 0; r < 14; r++) {
      float e = __expf(lg[r] - mx);
      se += e;
      sc += e * scl[r];
    }
    s1 = sc / (se * (1.f + 1e-8f));
  }

  float s2v;
  {
    // analytic relation LN stats
    float sR = Ssum[2 * 1568 + rowq] + Ssum[3 * 1568 + rowk];
    float ssR = SSsum[2 * 1568 + rowq] + SSsum[3 * 1568 + rowk] + dotR[pc];
    float mR = sR * (1.f / 512.f);
    float varR = ssR * (1.f / 512.f) - mR * mR;
    float rsR = rsqrtf(varR + EPSV);
    f16x2 nmR2 = pk2(-mR, -mR);
    f16x2 rsR2 = pk2(rsR, rsR);

    float acc = 0.f;
    const unsigned* rq = RqT + (size_t)sub * 1568 + rowq;
    const unsigned* rk = RkT + (size_t)sub * 1568 + rowk;
#pragma unroll
    for (int j = 0; j < 64; j++) {
      int dd = 4 * j + sub;
      uint4 tr = sTR[dd];
      f16x2 z2 = H2(rq[(size_t)j * 4 * 1568]) + H2(rk[(size_t)j * 4 * 1568]);
      f16x2 u2 = (z2 + nmR2) * rsR2;
      f16x2 h2 = __builtin_elementwise_max(u2 * H2(tr.x) + H2(tr.y), zero2);
      acc = __builtin_amdgcn_fdot2(h2, H2(tr.z), acc, false);
    }
    s2v = qsum(acc);
  }

  float gin = s1 + s2v + cconstp[0];
  float gate = 1.f / (1.f + __expf(-gin));
  if (valid && sub == 0) gfac[pid] = 1.f + gate;
}

// ---------- gated softmax attention, one block per (b,h); ao in f16 ----------
__global__ __launch_bounds__(256) void attn(const float* __restrict__ qb,
                                            const float* __restrict__ kb,
                                            const float* __restrict__ vb,
                                            const float* __restrict__ gfac,
                                            f16* __restrict__ aoh) {
  int b = blockIdx.x >> 3, h = blockIdx.x & 7;
  __shared__ float Kh[64][65];
  __shared__ float Vh[49][65];
  __shared__ float G[2401];
  int tid = threadIdx.x;
  for (int i = tid; i < 49 * 64; i += 256) {
    int k = i >> 6, d = i & 63;
    size_t off = (((size_t)(b * 49 + k)) << 9) + h * 64 + d;
    Kh[k][d] = kb[off];
    Vh[k][d] = vb[off];
  }
  for (int i = tid; i < 15 * 64; i += 256) {
    Kh[49 + (i >> 6)][i & 63] = 0.f;
  }
  for (int i = tid; i < 2401; i += 256) G[i] = gfac[b * 2401 + i];
  __syncthreads();
  int wave = tid >> 6, lane = tid & 63;
  for (int q = wave; q < 49; q += 4) {
    float qv = qb[(((size_t)(b * 49 + q)) << 9) + h * 64 + lane];
    float dot = 0.f;
#pragma unroll
    for (int d = 0; d < 64; d++) dot += __shfl(qv, d, 64) * Kh[lane][d];
    float enh = (lane < 49) ? dot * SCALEC * G[q * 49 + lane] : -1e30f;
    float mxv = wmax(enh);
    float e = (lane < 49) ? __expf(enh - mxv) : 0.f;
    float ssum = wsum(e);
    float w = e / ssum;
    float out = 0.f;
#pragma unroll
    for (int k = 0; k < 49; k++) out += __shfl(w, k, 64) * Vh[k][lane];
    aoh[(((size_t)(b * 49 + q)) << 9) + h * 64 + lane] = (f16)out;
  }
}

// ---------- launch ----------
extern "C" void kernel_launch(void* const* d_in, const int* in_sizes, int n_in,
                              void* d_out, int out_size, void* d_ws, size_t ws_size,
                              hipStream_t stream) {
  const float* queries = (const float*)d_in[0];
  const float* keys = (const float*)d_in[1];
  const float* values = (const float*)d_in[2];
  const float* Wq = (const float*)d_in[3];
  const float* bq = (const float*)d_in[4];
  const float* Wk = (const float*)d_in[5];
  const float* bk = (const float*)d_in[6];
  const float* Wv = (const float*)d_in[7];
  const float* bv = (const float*)d_in[8];
  const float* Wo = (const float*)d_in[9];
  const float* bo = (const float*)d_in[10];
  const float* rel_embed = (const float*)d_in[11];
  const float* Wproj = (const float*)d_in[12];
  const float* bproj = (const float*)d_in[13];
  const float* Wgate = (const float*)d_in[14];
  const float* bgate = (const float*)d_in[15];
  const float* Wc1 = (const float*)d_in[16];
  const float* bc1 = (const float*)d_in[17];
  const float* gc = (const float*)d_in[18];
  const float* bcln = (const float*)d_in[19];
  const float* Wc2 = (const float*)d_in[20];
  const float* bc2 = (const float*)d_in[21];
  const float* Wr1 = (const float*)d_in[22];
  const float* br1 = (const float*)d_in[23];
  const float* gr = (const float*)d_in[24];
  const float* brln = (const float*)d_in[25];
  const float* Wr2 = (const float*)d_in[26];
  const float* br2 = (const float*)d_in[27];
  const float* convW = (const float*)d_in[28];
  // d_in[29] = convb: cancelled by BatchNorm(affine=False)

  float* W = (float*)d_ws;
  size_t o = 0;
  f16* Qp = (f16*)(W + o); o += 663552;
  f16* Wtb = (f16*)(W + o); o += 1179648;
  f16* WqT = (f16*)(W + o); o += 131072;
  f16* WkT = (f16*)(W + o); o += 131072;
  f16* WvT = (f16*)(W + o); o += 131072;
  f16* WoT = (f16*)(W + o); o += 131072;
  f16* Wc1aT = (f16*)(W + o); o += 65536;
  f16* Wc1bT = (f16*)(W + o); o += 65536;
  f16* Wr1aT = (f16*)(W + o); o += 131072;
  f16* Wr1bT = (f16*)(W + o); o += 131072;
  float* hbuf = W + o; o += 802816;
  f16* eqh = (f16*)(W + o); o += 401408;
  f16* ekh = (f16*)(W + o); o += 401408;
  f16* evh = (f16*)(W + o); o += 401408;
  float* qbuf = W + o; o += 802816;
  float* kbuf = W + o; o += 802816;
  float* vbuf = W + o; o += 802816;
  float* Cqw = W + o; o += 401408;
  float* Ckw = W + o; o += 401408;
  float* Rqw = W + o; o += 802816;
  float* Rkw = W + o; o += 802816;
  f16* aoh = (f16*)(W + o); o += 200704;
  float* gf = W + o; o += 76832;
  float* mu = W + o; o += 512;
  float* rsg = W + o; o += 512;
  float* crel = W + o; o += 16;
  float* wrg = W + o; o += 512;
  float* ccst = W + o; o += 16;
  unsigned* CqT2 = (unsigned*)(W + o); o += 200704;  // [128][1568]
  unsigned* CkT2 = (unsigned*)(W + o); o += 200704;
  unsigned* RqT2 = (unsigned*)(W + o); o += 401408;  // [256][1568]
  unsigned* RkT2 = (unsigned*)(W + o); o += 401408;
  f16* Cqh = (f16*)(W + o); o += 200704;             // [1568][256] f16
  f16* Ckh = (f16*)(W + o); o += 200704;
  f16* Rqh = (f16*)(W + o); o += 401408;             // [1568][512] f16
  f16* Rkh = (f16*)(W + o); o += 401408;
  float* Ssum = W + o; o += 6272;                    // [4][1568]
  float* SSsum = W + o; o += 6272;
  float* dotC = W + o; o += 76832;
  float* dotR = W + o; o += 76832;

  hipLaunchKernelGGL(prep, dim3(784 + 5184 + 1024), dim3(256), 0, stream,
                     queries, convW, hbuf, Qp, Wtb);
  hipLaunchKernelGGL(smalls_kernel, dim3(129), dim3(256), 0, stream, Wproj, Wgate,
                     rel_embed, bproj, br2, bgate, Wr2, crel, wrg, ccst);

  TJobs tj;
  tj.src[0] = Wq;  tj.dst[0] = WqT;  tj.cols[0] = 512;
  tj.src[1] = Wk;  tj.dst[1] = WkT;  tj.cols[1] = 512;
  tj.src[2] = Wv;  tj.dst[2] = WvT;  tj.cols[2] = 512;
  tj.src[3] = Wo;  tj.dst[3] = WoT;  tj.cols[3] = 512;
  tj.src[4] = Wc1;             tj.dst[4] = Wc1aT; tj.cols[4] = 256;
  tj.src[5] = Wc1 + 512 * 256; tj.dst[5] = Wc1bT; tj.cols[5] = 256;
  tj.src[6] = Wr1;             tj.dst[6] = Wr1aT; tj.cols[6] = 512;
  tj.src[7] = Wr1 + 512 * 512; tj.dst[7] = Wr1bT; tj.cols[7] = 512;
  hipLaunchKernelGGL(transpose_w, dim3(16, 16, 8), dim3(256), 0, stream, tj);

  hipLaunchKernelGGL(conv_mfma, dim3(8, 25, 8), dim3(256), 0, stream, Qp, Wtb, hbuf);
  hipLaunchKernelGGL(bn_stats, dim3(512), dim3(256), 0, stream, hbuf, mu, rsg);
  hipLaunchKernelGGL(fuse_xs, dim3(3136), dim3(256), 0, stream, hbuf, mu, rsg,
                     queries, keys, values, eqh, ekh, evh);

  MJobs jb;
  for (int z = 0; z < 7; z++) jb.Ch[z] = nullptr;
  jb.A[0] = eqh; jb.BT[0] = WqT;   jb.bias[0] = bq;      jb.C[0] = qbuf; jb.N[0] = 512;
  jb.A[1] = ekh; jb.BT[1] = WkT;   jb.bias[1] = bk;      jb.C[1] = kbuf; jb.N[1] = 512;
  jb.A[2] = evh; jb.BT[2] = WvT;   jb.bias[2] = bv;      jb.C[2] = vbuf; jb.N[2] = 512;
  jb.A[3] = eqh; jb.BT[3] = Wc1aT; jb.bias[3] = bc1;     jb.C[3] = Cqw;  jb.N[3] = 256; jb.Ch[3] = Cqh;
  jb.A[4] = ekh; jb.BT[4] = Wc1bT; jb.bias[4] = nullptr; jb.C[4] = Ckw;  jb.N[4] = 256; jb.Ch[4] = Ckh;
  jb.A[5] = eqh; jb.BT[5] = Wr1aT; jb.bias[5] = br1;     jb.C[5] = Rqw;  jb.N[5] = 512; jb.Ch[5] = Rqh;
  jb.A[6] = ekh; jb.BT[6] = Wr1bT; jb.bias[6] = nullptr; jb.C[6] = Rkw;  jb.N[6] = 512; jb.Ch[6] = Rkh;
  hipLaunchKernelGGL(gemm_mf, dim3(8, 25, 7), dim3(256), 0, stream, jb);

  RSJobs rj;
  rj.src[0] = Cqw; rj.w[0] = 256;
  rj.src[1] = Ckw; rj.w[1] = 256;
  rj.src[2] = Rqw; rj.w[2] = 512;
  rj.src[3] = Rkw; rj.w[3] = 512;
  hipLaunchKernelGGL(row_sums, dim3(392, 4), dim3(256), 0, stream, rj, Ssum, SSsum);

  T2Jobs t2;
  t2.src[0] = Cqw; t2.dst[0] = CqT2; t2.C[0] = 256;
  t2.src[1] = Ckw; t2.dst[1] = CkT2; t2.C[1] = 256;
  t2.src[2] = Rqw; t2.dst[2] = RqT2; t2.C[2] = 512;
  t2.src[3] = Rkw; t2.dst[3] = RkT2; t2.C[3] = 512;
  hipLaunchKernelGGL(t2h, dim3(16, 49, 4), dim3(256), 0, stream, t2);

  hipLaunchKernelGGL(gram_mfma, dim3(64), dim3(256), 0, stream, Cqh, Ckh, Rqh, Rkh,
                     dotC, dotR);

  hipLaunchKernelGGL(pair_gate, dim3((NPAIR * 4 + 255) / 256), dim3(256), 0, stream,
                     CqT2, CkT2, RqT2, RkT2, Wc2, bc2, gc, bcln, gr, brln, crel,
                     wrg, ccst, Ssum, SSsum, dotC, dotR, gf);
  hipLaunchKernelGGL(attn, dim3(256), dim3(256), 0, stream, qbuf, kbuf, vbuf, gf, aoh);

  MJobs j2;
  for (int z = 0; z < 7; z++) {
    j2.A[z] = nullptr; j2.BT[z] = nullptr; j2.bias[z] = nullptr;
    j2.C[z] = nullptr; j2.Ch[z] = nullptr; j2.N[z] = 0;
  }
  j2.A[0] = aoh; j2.BT[0] = WoT; j2.bias[0] = bo; j2.C[0] = (float*)d_out; j2.N[0] = 512;
  hipLaunchKernelGGL(gemm_mf, dim3(8, 25, 1), dim3(256), 0, stream, j2);
}

// Round 8
// 348.772 us; speedup vs baseline: 1.0320x; 1.0320x over previous
//
#include <hip/hip_runtime.h>
#include <math.h>

typedef _Float16 f16;
typedef _Float16 f16x2 __attribute__((ext_vector_type(2)));
typedef _Float16 f16x8 __attribute__((ext_vector_type(8)));
typedef float f32x4 __attribute__((ext_vector_type(4)));

static constexpr int Mrows = 1568;   // 32*49
static constexpr int NPAIR = 76832;  // 32*49*49
static constexpr float SCALEC = 0.125f;
#define EPSV 1e-5f

// ---------- helpers ----------
__device__ inline float wsum(float v) {
#pragma unroll
  for (int m = 32; m >= 1; m >>= 1) v += __shfl_xor(v, m, 64);
  return v;
}
__device__ inline float wmax(float v) {
#pragma unroll
  for (int m = 32; m >= 1; m >>= 1) v = fmaxf(v, __shfl_xor(v, m, 64));
  return v;
}
__device__ inline void gld16(const void* g, void* l) {
  __builtin_amdgcn_global_load_lds((const __attribute__((address_space(1))) void*)g,
                                   (__attribute__((address_space(3))) void*)l, 16, 0, 0);
}
__device__ inline f16x2 H2(unsigned u) { return __builtin_bit_cast(f16x2, u); }
__device__ inline unsigned U32(f16x2 h) { return __builtin_bit_cast(unsigned, h); }
__device__ inline f16x2 pk2(float a, float b) {
  return __builtin_bit_cast(f16x2, __builtin_amdgcn_cvt_pkrtz(a, b));
}
__device__ inline float qsum(float v) {
  v += __shfl_xor(v, 1, 64);
  v += __shfl_xor(v, 2, 64);
  return v;
}

// ================= SETUP mega-kernel =================
// blocks [0,784): zero h | [784,5968): Qp | [5968,6992): Wtb
// [6992,8784): 8 weight transposes | [8784,8913): smalls (crel/wrg/cconst)
struct SetupW { const float* src[8]; f16* dst[8]; int cols[8]; };
__global__ __launch_bounds__(256) void setup(
    const float* __restrict__ queries, const float* __restrict__ convW,
    const float* __restrict__ Wproj, const float* __restrict__ Wgate,
    const float* __restrict__ rel_embed, const float* __restrict__ bproj,
    const float* __restrict__ br2, const float* __restrict__ bgate,
    const float* __restrict__ Wr2, SetupW tw, float* __restrict__ h,
    f16* __restrict__ Qp, f16* __restrict__ Wtb, float* __restrict__ crel,
    float* __restrict__ wrg, float* __restrict__ cconst) {
  __shared__ float tile[32][33];
  __shared__ float pg[64];
  int bx = blockIdx.x;
  int tid = threadIdx.x;
  if (bx < 784) {
    ((float4*)h)[bx * 256 + tid] = make_float4(0.f, 0.f, 0.f, 0.f);
  } else if (bx < 5968) {
    int idx = (bx - 784) * 256 + tid;
    int c = idx & 511;
    int iijj = (idx >> 9) % 81;
    int b = idx / (81 * 512);
    int ii = iijj / 9, jj = iijj % 9;
    float v = 0.f;
    if (ii >= 1 && ii <= 7 && jj >= 1 && jj <= 7)
      v = queries[(((size_t)(b * 49 + (ii - 1) * 7 + (jj - 1))) << 9) + c];
    Qp[idx] = (f16)v;
  } else if (bx < 6992) {
    int idx = (bx - 5968) * 256 + tid;
    int o = idx >> 9, c = idx & 511;
    const float* s = convW + (size_t)o * 4608 + c * 9;
    f16* d = Wtb + (size_t)o * 4608 + c;
#pragma unroll
    for (int t = 0; t < 9; t++) d[t * 512] = (f16)s[t];
  } else if (bx < 8784) {
    // weight transpose+convert: dst[n][k] = (f16)src[k][n], K=512
    int l = bx - 6992;
    int z = 0;
    while (z < 8) {
      int nb = (tw.cols[z] >> 5) * 16;
      if (l < nb) break;
      l -= nb;
      z++;
    }
    int cols = tw.cols[z];
    int nx = cols >> 5;
    int n0 = (l % nx) * 32;
    int k0 = (l / nx) * 32;
    const float* src = tw.src[z];
    f16* dst = tw.dst[z];
    int c = tid & 31, r0 = tid >> 5;
#pragma unroll
    for (int i = 0; i < 4; i++) {
      int r = r0 + i * 8;
      tile[r][c] = src[(size_t)(k0 + r) * cols + n0 + c];
    }
    __syncthreads();
#pragma unroll
    for (int i = 0; i < 4; i++) {
      int r = r0 + i * 8;
      dst[(size_t)(n0 + r) * 512 + k0 + c] = (f16)tile[c][r];
    }
  } else {
    // smalls: crel[14], wrg[512], cconst
    int l = bx - 8784;
    int wv = tid >> 6, lane = tid & 63;
    if (l == 0) {
      for (int o = wv; o < 64; o += 4) {
        float s = 0.f;
        for (int d = lane; d < 512; d += 64) s += Wproj[o * 512 + d] * Wgate[d];
        s = wsum(s);
        if (lane == 0) pg[o] = s;
      }
      if (wv == 3) {
        float s = 0.f;
        for (int d = lane; d < 512; d += 64) s += (bproj[d] + br2[d]) * Wgate[d];
        s = wsum(s);
        if (lane == 0) cconst[0] = s + bgate[0];
      }
      __syncthreads();
      if (tid < 14) {
        float s = 0.f;
        for (int dk = 0; dk < 64; dk++) s += rel_embed[tid * 64 + dk] * pg[dk];
        crel[tid] = s;
      }
    } else {
      int d = (l - 1) * 4 + wv;  // 128 blocks * 4 waves = 512
      float s = 0.f;
      for (int d2 = lane; d2 < 512; d2 += 64)
        s += Wr2[(size_t)d * 512 + d2] * Wgate[d2];
      s = wsum(s);
      if (lane == 0) wrg[d] = s;
    }
  }
}

// ================= MID mega-kernel =================
// blocks [0,1568): row_sums | [1568,3920): t2h | [3920,3984): gram
struct MidA {
  const float* rs_src[4]; int rs_w[4];
  const float* t2_src[4]; unsigned* t2_dst[4]; int t2_C[4];
  const f16* gA[2]; const f16* gB[2]; float* gOut[2]; int gK[2];
};
__global__ __launch_bounds__(256) void mid(MidA ma, float* __restrict__ Ssum,
                                           float* __restrict__ SSsum) {
  __shared__ float tile[32][33];
  __shared__ f16 As2[2048];
  __shared__ f16 Bs2[2048];
  int bx = blockIdx.x;
  int tid = threadIdx.x;
  if (bx < 1568) {
    int j = bx / 392, xb = bx % 392;
    int w = ma.rs_w[j];
    const float* src = ma.rs_src[j];
    int row = xb * 4 + (tid >> 6);
    int lane = tid & 63;
    float s = 0.f, ss = 0.f;
    for (int c = lane; c < w; c += 64) {
      float v = src[(size_t)row * w + c];
      s += v;
      ss += v * v;
    }
    s = wsum(s);
    ss = wsum(ss);
    if (lane == 0) {
      Ssum[j * 1568 + row] = s;
      SSsum[j * 1568 + row] = ss;
    }
  } else if (bx < 3920) {
    int l = bx - 1568;
    int z = 0;
    while (z < 4) {
      int nb = (ma.t2_C[z] >> 5) * 49;
      if (l < nb) break;
      l -= nb;
      z++;
    }
    int C = ma.t2_C[z];
    int nx = C >> 5;
    int c0 = (l % nx) * 32;
    int r0 = (l / nx) * 32;
    const float* src = ma.t2_src[z];
    unsigned* dst = ma.t2_dst[z];
    int cc = tid & 31, rr = tid >> 5;
#pragma unroll
    for (int i = 0; i < 4; i++)
      tile[cc][rr + i * 8] = src[(size_t)(r0 + rr + i * 8) * C + c0 + cc];
    __syncthreads();
    int r = tid & 31, cp = tid >> 5;
#pragma unroll
    for (int i = 0; i < 2; i++) {
      int c = cp + i * 8;
      f16x2 p = pk2(tile[2 * c][r], tile[2 * c + 1][r]);
      dst[(size_t)((c0 >> 1) + c) * 1568 + r0 + r] = U32(p);
    }
  } else {
    // batched Gram via MFMA: out[b][q][k] = 2 * (A_row_q . B_row_k)
    int l = bx - 3920;
    int z = l >> 5, b = l & 31;
    int K = ma.gK[z];
    const f16* A = ma.gA[z] + (size_t)b * 49 * K;
    const f16* BT = ma.gB[z] + (size_t)b * 49 * K;
    float* out = ma.gOut[z] + (size_t)b * 2401;
    int lane = tid & 63, wv = tid >> 6;
    int kq = (tid >> 4) & 3, mm = tid & 15;
    int rowA = wv * 16 + mm;
    if (rowA > 48) rowA = 48;
    const f16* aSrc = A + (size_t)rowA * K + kq * 8;
    const f16* bSrc = BT + (size_t)rowA * K + kq * 8;
    f16* aDst = &As2[wv * 512];
    f16* bDst = &Bs2[wv * 512];
    f32x4 acc[4];
#pragma unroll
    for (int i = 0; i < 4; i++) acc[i] = (f32x4){0.f, 0.f, 0.f, 0.f};
    int steps = K >> 5;
    for (int s = 0; s < steps; s++) {
      gld16(aSrc + s * 32, aDst);
      gld16(bSrc + s * 32, bDst);
      __syncthreads();
      f16x8 a = *(const f16x8*)&As2[(wv << 9) + (lane << 3)];
#pragma unroll
      for (int nb = 0; nb < 4; nb++) {
        f16x8 bf = *(const f16x8*)&Bs2[(nb << 9) + (lane << 3)];
        acc[nb] = __builtin_amdgcn_mfma_f32_16x16x32_f16(a, bf, acc[nb], 0, 0, 0);
      }
      __syncthreads();
    }
    int r0 = wv * 16 + ((lane >> 4) << 2);
    int cw = lane & 15;
#pragma unroll
    for (int nb = 0; nb < 4; nb++) {
      int col = nb * 16 + cw;
#pragma unroll
      for (int r = 0; r < 4; r++) {
        int row = r0 + r;
        if (row < 49 && col < 49) out[row * 49 + col] = 2.f * acc[nb][r];
      }
    }
  }
}

// ---------- conv as implicit-im2col MFMA GEMM, split-K=8, atomicAdd into h ----------
__global__ __launch_bounds__(256) void conv_mfma(const f16* __restrict__ Qp,
                                                 const f16* __restrict__ Wtb,
                                                 float* __restrict__ h) {
  __shared__ f16 As2[2048];
  __shared__ f16 Bs2[2048];
  int tid = threadIdx.x;
  int n0 = blockIdx.x * 64;
  int m0 = blockIdx.y * 64;
  int kb = blockIdx.z * 576;
  int lane = tid & 63, wv = tid >> 6;
  int kq = (tid >> 4) & 3, mm = tid & 15;
  int rowA = m0 + wv * 16 + mm;
  if (rowA > Mrows - 1) rowA = Mrows - 1;
  int b = rowA / 49, p = rowA % 49;
  int pi = p / 7, pj = p % 7;
  const f16* qbase = Qp + (size_t)b * 81 * 512 + kq * 8;
  int rowB = n0 + wv * 16 + mm;
  const f16* bSrc = Wtb + (size_t)rowB * 4608 + kq * 8 + kb;
  f16* aDst = &As2[wv * 512];
  f16* bDst = &Bs2[wv * 512];
  f32x4 acc[4];
#pragma unroll
  for (int i = 0; i < 4; i++) acc[i] = (f32x4){0.f, 0.f, 0.f, 0.f};
  for (int s = 0; s < 18; s++) {
    int k0 = kb + s * 32;
    int t = k0 >> 9, c0 = k0 & 511;
    int ti = t / 3, tj = t - ti * 3;
    const f16* aSrc = qbase + (size_t)((pi + ti) * 9 + (pj + tj)) * 512 + c0;
    gld16(aSrc, aDst);
    gld16(bSrc + s * 32, bDst);
    __syncthreads();
    f16x8 a = *(const f16x8*)&As2[(wv << 9) + (lane << 3)];
#pragma unroll
    for (int nb = 0; nb < 4; nb++) {
      f16x8 bf = *(const f16x8*)&Bs2[(nb << 9) + (lane << 3)];
      acc[nb] = __builtin_amdgcn_mfma_f32_16x16x32_f16(a, bf, acc[nb], 0, 0, 0);
    }
    __syncthreads();
  }
  int r0 = m0 + wv * 16 + ((lane >> 4) << 2);
  int cw = lane & 15;
#pragma unroll
  for (int nb = 0; nb < 4; nb++) {
    int col = n0 + nb * 16 + cw;
#pragma unroll
    for (int r = 0; r < 4; r++) {
      int row = r0 + r;
      if (row < Mrows) atomicAdd(&h[(size_t)row * 512 + col], acc[nb][r]);
    }
  }
}

// ---------- BatchNorm stats per channel ----------
__global__ __launch_bounds__(256) void bn_stats(const float* __restrict__ h,
                                                float* __restrict__ mu,
                                                float* __restrict__ rsg) {
  int c = blockIdx.x;
  int tid = threadIdx.x;
  float s = 0.f, ss = 0.f;
  for (int r = tid; r < Mrows; r += 256) {
    float v = h[(size_t)r * 512 + c];
    s += v;
    ss += v * v;
  }
  s = wsum(s);
  ss = wsum(ss);
  __shared__ float r1[4], r2[4];
  int wave = tid >> 6, lane = tid & 63;
  if (lane == 0) { r1[wave] = s; r2[wave] = ss; }
  __syncthreads();
  if (tid == 0) {
    float S = r1[0] + r1[1] + r1[2] + r1[3];
    float SS = r2[0] + r2[1] + r2[2] + r2[3];
    float m = S / (float)Mrows;
    float var = SS / (float)Mrows - m * m;
    mu[c] = m;
    rsg[c] = rsqrtf(var + EPSV);
  }
}

// ---------- xs = relu(bn(h)); eq/ek/ev (f16) ----------
__global__ __launch_bounds__(256) void fuse_xs(
    const float* __restrict__ h, const float* __restrict__ mu,
    const float* __restrict__ rsg, const float* __restrict__ Q,
    const float* __restrict__ Kin, const float* __restrict__ Vin,
    f16* __restrict__ eqh, f16* __restrict__ ekh, f16* __restrict__ evh) {
  int i = blockIdx.x * 256 + threadIdx.x;
  int c = i & 511;
  float xs = fmaxf((h[i] - mu[c]) * rsg[c], 0.f);
  eqh[i] = (f16)(xs + Q[i]);
  ekh[i] = (f16)(xs + Kin[i]);
  evh[i] = (f16)(xs + Vin[i]);
}

// ---------- generic MFMA GEMM (+optional f16 copy) ----------
struct MJobs {
  const f16* A[7]; const f16* BT[7]; const float* bias[7];
  float* C[7]; f16* Ch[7]; int N[7];
};
__global__ __launch_bounds__(256) void gemm_mf(MJobs jb) {
  int z = blockIdx.z;
  int N = jb.N[z];
  int n0 = blockIdx.x * 64;
  if (n0 >= N) return;
  int m0 = blockIdx.y * 64;
  const f16* A = jb.A[z];
  const f16* BT = jb.BT[z];
  __shared__ f16 As2[2048];
  __shared__ f16 Bs2[2048];
  int tid = threadIdx.x, lane = tid & 63, wv = tid >> 6;
  int kq = (tid >> 4) & 3, mm = tid & 15;
  int rowA = m0 + wv * 16 + mm;
  if (rowA > Mrows - 1) rowA = Mrows - 1;
  const f16* aSrc = A + (size_t)rowA * 512 + kq * 8;
  int rowB = n0 + wv * 16 + mm;
  const f16* bSrc = BT + (size_t)rowB * 512 + kq * 8;
  f16* aDst = &As2[wv * 512];
  f16* bDst = &Bs2[wv * 512];
  f32x4 acc[4];
#pragma unroll
  for (int i = 0; i < 4; i++) acc[i] = (f32x4){0.f, 0.f, 0.f, 0.f};
  for (int s = 0; s < 16; s++) {
    gld16(aSrc + s * 32, aDst);
    gld16(bSrc + s * 32, bDst);
    __syncthreads();
    f16x8 a = *(const f16x8*)&As2[(wv << 9) + (lane << 3)];
#pragma unroll
    for (int nb = 0; nb < 4; nb++) {
      f16x8 bf = *(const f16x8*)&Bs2[(nb << 9) + (lane << 3)];
      acc[nb] = __builtin_amdgcn_mfma_f32_16x16x32_f16(a, bf, acc[nb], 0, 0, 0);
    }
    __syncthreads();
  }
  const float* bias = jb.bias[z];
  float* C = jb.C[z];
  f16* Ch = jb.Ch[z];
  int r0 = m0 + wv * 16 + ((lane >> 4) << 2);
  int cw = lane & 15;
#pragma unroll
  for (int nb = 0; nb < 4; nb++) {
    int col = n0 + nb * 16 + cw;
    float bv = bias ? bias[col] : 0.f;
#pragma unroll
    for (int r = 0; r < 4; r++) {
      int row = r0 + r;
      if (row < Mrows) {
        float v = acc[nb][r] + bv;
        C[(size_t)row * N + col] = v;
        if (Ch) Ch[(size_t)row * N + col] = (f16)v;
      }
    }
  }
}

// ---------- pair gate: quad-per-pair, single pass (analytic LN stats) ----------
__global__ __launch_bounds__(256) void pair_gate(
    const unsigned* __restrict__ CqT, const unsigned* __restrict__ CkT,
    const unsigned* __restrict__ RqT, const unsigned* __restrict__ RkT,
    const float* __restrict__ Wc2, const float* __restrict__ bc2,
    const float* __restrict__ gc, const float* __restrict__ bcln,
    const float* __restrict__ gr, const float* __restrict__ brln,
    const float* __restrict__ crel, const float* __restrict__ wrg,
    const float* __restrict__ cconstp, const float* __restrict__ Ssum,
    const float* __restrict__ SSsum, const float* __restrict__ dotC,
    const float* __restrict__ dotR, float* __restrict__ gfac) {
  __shared__ uint4 sTC[512];
  __shared__ uint4 sTR[256];
  __shared__ float scl[14], sb2[14];
  int tid = threadIdx.x;
  if (tid < 128) {
    int dd = tid;
    unsigned w[16];
    w[0] = U32(pk2(gc[2 * dd], gc[2 * dd + 1]));
    w[1] = U32(pk2(bcln[2 * dd], bcln[2 * dd + 1]));
#pragma unroll
    for (int r = 0; r < 14; r++)
      w[2 + r] = U32(pk2(Wc2[(2 * dd) * 14 + r], Wc2[(2 * dd + 1) * 14 + r]));
#pragma unroll
    for (int j = 0; j < 4; j++)
      sTC[dd * 4 + j] = make_uint4(w[4 * j], w[4 * j + 1], w[4 * j + 2], w[4 * j + 3]);
  }
  {
    int dd = tid;
    sTR[dd] = make_uint4(U32(pk2(gr[2 * dd], gr[2 * dd + 1])),
                         U32(pk2(brln[2 * dd], brln[2 * dd + 1])),
                         U32(pk2(wrg[2 * dd], wrg[2 * dd + 1])), 0u);
  }
  if (tid < 14) { scl[tid] = crel[tid]; sb2[tid] = bc2[tid]; }
  __syncthreads();

  int gidx = blockIdx.x * 256 + tid;
  int pid = gidx >> 2;
  int sub = gidx & 3;
  bool valid = pid < NPAIR;
  int pc = valid ? pid : NPAIR - 1;
  int b = pc / 2401;
  int r2 = pc % 2401;
  int q = r2 / 49, k = r2 % 49;
  int rowq = b * 49 + q, rowk = b * 49 + k;
  const f16x2 zero2 = {(f16)0.f, (f16)0.f};

  float s1;
  {
    float sC = Ssum[rowq] + Ssum[1568 + rowk];
    float ssC = SSsum[rowq] + SSsum[1568 + rowk] + dotC[pc];
    float mC = sC * (1.f / 256.f);
    float var = ssC * (1.f / 256.f) - mC * mC;
    float rsC = rsqrtf(var + EPSV);
    f16x2 nm2 = pk2(-mC, -mC);
    f16x2 rs2 = pk2(rsC, rsC);

    float lg[14];
#pragma unroll
    for (int r = 0; r < 14; r++) lg[r] = 0.f;
    const unsigned* cq = CqT + (size_t)sub * 1568 + rowq;
    const unsigned* ck = CkT + (size_t)sub * 1568 + rowk;
#pragma unroll
    for (int j = 0; j < 32; j++) {
      int dd = 4 * j + sub;
      uint4 t0 = sTC[dd * 4 + 0];
      uint4 t1 = sTC[dd * 4 + 1];
      uint4 t2 = sTC[dd * 4 + 2];
      uint4 t3 = sTC[dd * 4 + 3];
      f16x2 z2 = H2(cq[(size_t)j * 4 * 1568]) + H2(ck[(size_t)j * 4 * 1568]);
      f16x2 u2 = (z2 + nm2) * rs2;
      f16x2 h2 = __builtin_elementwise_max(u2 * H2(t0.x) + H2(t0.y), zero2);
      lg[0] = __builtin_amdgcn_fdot2(h2, H2(t0.z), lg[0], false);
      lg[1] = __builtin_amdgcn_fdot2(h2, H2(t0.w), lg[1], false);
      lg[2] = __builtin_amdgcn_fdot2(h2, H2(t1.x), lg[2], false);
      lg[3] = __builtin_amdgcn_fdot2(h2, H2(t1.y), lg[3], false);
      lg[4] = __builtin_amdgcn_fdot2(h2, H2(t1.z), lg[4], false);
      lg[5] = __builtin_amdgcn_fdot2(h2, H2(t1.w), lg[5], false);
      lg[6] = __builtin_amdgcn_fdot2(h2, H2(t2.x), lg[6], false);
      lg[7] = __builtin_amdgcn_fdot2(h2, H2(t2.y), lg[7], false);
      lg[8] = __builtin_amdgcn_fdot2(h2, H2(t2.z), lg[8], false);
      lg[9] = __builtin_amdgcn_fdot2(h2, H2(t2.w), lg[9], false);
      lg[10] = __builtin_amdgcn_fdot2(h2, H2(t3.x), lg[10], false);
      lg[11] = __builtin_amdgcn_fdot2(h2, H2(t3.y), lg[11], false);
      lg[12] = __builtin_amdgcn_fdot2(h2, H2(t3.z), lg[12], false);
      lg[13] = __builtin_amdgcn_fdot2(h2, H2(t3.w), lg[13], false);
    }
#pragma unroll
    for (int r = 0; r < 14; r++) lg[r] = qsum(lg[r]) + sb2[r];

    float mx = lg[0];
#pragma unroll
    for (int r = 1; r < 14; r++) mx = fmaxf(mx, lg[r]);
    float se = 0.f, sc = 0.f;
#pragma unroll
    for (int r = 0; r < 14; r++) {
      float e = __expf(lg[r] - mx);
      se += e;
      sc += e * scl[r];
    }
    s1 = sc / (se * (1.f + 1e-8f));
  }

  float s2v;
  {
    float sR = Ssum[2 * 1568 + rowq] + Ssum[3 * 1568 + rowk];
    float ssR = SSsum[2 * 1568 + rowq] + SSsum[3 * 1568 + rowk] + dotR[pc];
    float mR = sR * (1.f / 512.f);
    float varR = ssR * (1.f / 512.f) - mR * mR;
    float rsR = rsqrtf(varR + EPSV);
    f16x2 nmR2 = pk2(-mR, -mR);
    f16x2 rsR2 = pk2(rsR, rsR);

    float acc = 0.f;
    const unsigned* rq = RqT + (size_t)sub * 1568 + rowq;
    const unsigned* rk = RkT + (size_t)sub * 1568 + rowk;
#pragma unroll
    for (int j = 0; j < 64; j++) {
      int dd = 4 * j + sub;
      uint4 tr = sTR[dd];
      f16x2 z2 = H2(rq[(size_t)j * 4 * 1568]) + H2(rk[(size_t)j * 4 * 1568]);
      f16x2 u2 = (z2 + nmR2) * rsR2;
      f16x2 h2 = __builtin_elementwise_max(u2 * H2(tr.x) + H2(tr.y), zero2);
      acc = __builtin_amdgcn_fdot2(h2, H2(tr.z), acc, false);
    }
    s2v = qsum(acc);
  }

  float gin = s1 + s2v + cconstp[0];
  float gate = 1.f / (1.f + __expf(-gin));
  if (valid && sub == 0) gfac[pid] = 1.f + gate;
}

// ---------- gated softmax attention, one block per (b,h); ao in f16 ----------
__global__ __launch_bounds__(256) void attn(const float* __restrict__ qb,
                                            const float* __restrict__ kb,
                                            const float* __restrict__ vb,
                                            const float* __restrict__ gfac,
                                            f16* __restrict__ aoh) {
  int b = blockIdx.x >> 3, h = blockIdx.x & 7;
  __shared__ float Kh[64][65];
  __shared__ float Vh[49][65];
  __shared__ float G[2401];
  int tid = threadIdx.x;
  for (int i = tid; i < 49 * 64; i += 256) {
    int k = i >> 6, d = i & 63;
    size_t off = (((size_t)(b * 49 + k)) << 9) + h * 64 + d;
    Kh[k][d] = kb[off];
    Vh[k][d] = vb[off];
  }
  for (int i = tid; i < 15 * 64; i += 256) {
    Kh[49 + (i >> 6)][i & 63] = 0.f;
  }
  for (int i = tid; i < 2401; i += 256) G[i] = gfac[b * 2401 + i];
  __syncthreads();
  int wave = tid >> 6, lane = tid & 63;
  for (int q = wave; q < 49; q += 4) {
    float qv = qb[(((size_t)(b * 49 + q)) << 9) + h * 64 + lane];
    float dot = 0.f;
#pragma unroll
    for (int d = 0; d < 64; d++) dot += __shfl(qv, d, 64) * Kh[lane][d];
    float enh = (lane < 49) ? dot * SCALEC * G[q * 49 + lane] : -1e30f;
    float mxv = wmax(enh);
    float e = (lane < 49) ? __expf(enh - mxv) : 0.f;
    float ssum = wsum(e);
    float w = e / ssum;
    float out = 0.f;
#pragma unroll
    for (int k = 0; k < 49; k++) out += __shfl(w, k, 64) * Vh[k][lane];
    aoh[(((size_t)(b * 49 + q)) << 9) + h * 64 + lane] = (f16)out;
  }
}

// ---------- launch ----------
extern "C" void kernel_launch(void* const* d_in, const int* in_sizes, int n_in,
                              void* d_out, int out_size, void* d_ws, size_t ws_size,
                              hipStream_t stream) {
  const float* queries = (const float*)d_in[0];
  const float* keys = (const float*)d_in[1];
  const float* values = (const float*)d_in[2];
  const float* Wq = (const float*)d_in[3];
  const float* bq = (const float*)d_in[4];
  const float* Wk = (const float*)d_in[5];
  const float* bk = (const float*)d_in[6];
  const float* Wv = (const float*)d_in[7];
  const float* bv = (const float*)d_in[8];
  const float* Wo = (const float*)d_in[9];
  const float* bo = (const float*)d_in[10];
  const float* rel_embed = (const float*)d_in[11];
  const float* Wproj = (const float*)d_in[12];
  const float* bproj = (const float*)d_in[13];
  const float* Wgate = (const float*)d_in[14];
  const float* bgate = (const float*)d_in[15];
  const float* Wc1 = (const float*)d_in[16];
  const float* bc1 = (const float*)d_in[17];
  const float* gc = (const float*)d_in[18];
  const float* bcln = (const float*)d_in[19];
  const float* Wc2 = (const float*)d_in[20];
  const float* bc2 = (const float*)d_in[21];
  const float* Wr1 = (const float*)d_in[22];
  const float* br1 = (const float*)d_in[23];
  const float* gr = (const float*)d_in[24];
  const float* brln = (const float*)d_in[25];
  const float* Wr2 = (const float*)d_in[26];
  const float* br2 = (const float*)d_in[27];
  const float* convW = (const float*)d_in[28];
  // d_in[29] = convb: cancelled by BatchNorm(affine=False)

  float* W = (float*)d_ws;
  size_t o = 0;
  f16* Qp = (f16*)(W + o); o += 663552;
  f16* Wtb = (f16*)(W + o); o += 1179648;
  f16* WqT = (f16*)(W + o); o += 131072;
  f16* WkT = (f16*)(W + o); o += 131072;
  f16* WvT = (f16*)(W + o); o += 131072;
  f16* WoT = (f16*)(W + o); o += 131072;
  f16* Wc1aT = (f16*)(W + o); o += 65536;
  f16* Wc1bT = (f16*)(W + o); o += 65536;
  f16* Wr1aT = (f16*)(W + o); o += 131072;
  f16* Wr1bT = (f16*)(W + o); o += 131072;
  float* hbuf = W + o; o += 802816;
  f16* eqh = (f16*)(W + o); o += 401408;
  f16* ekh = (f16*)(W + o); o += 401408;
  f16* evh = (f16*)(W + o); o += 401408;
  float* qbuf = W + o; o += 802816;
  float* kbuf = W + o; o += 802816;
  float* vbuf = W + o; o += 802816;
  float* Cqw = W + o; o += 401408;
  float* Ckw = W + o; o += 401408;
  float* Rqw = W + o; o += 802816;
  float* Rkw = W + o; o += 802816;
  f16* aoh = (f16*)(W + o); o += 200704;
  float* gf = W + o; o += 76832;
  float* mu = W + o; o += 512;
  float* rsg = W + o; o += 512;
  float* crel = W + o; o += 16;
  float* wrg = W + o; o += 512;
  float* ccst = W + o; o += 16;
  unsigned* CqT2 = (unsigned*)(W + o); o += 200704;  // [128][1568]
  unsigned* CkT2 = (unsigned*)(W + o); o += 200704;
  unsigned* RqT2 = (unsigned*)(W + o); o += 401408;  // [256][1568]
  unsigned* RkT2 = (unsigned*)(W + o); o += 401408;
  f16* Cqh = (f16*)(W + o); o += 200704;             // [1568][256] f16
  f16* Ckh = (f16*)(W + o); o += 200704;
  f16* Rqh = (f16*)(W + o); o += 401408;             // [1568][512] f16
  f16* Rkh = (f16*)(W + o); o += 401408;
  float* Ssum = W + o; o += 6272;                    // [4][1568]
  float* SSsum = W + o; o += 6272;
  float* dotC = W + o; o += 76832;
  float* dotR = W + o; o += 76832;

  SetupW tw;
  tw.src[0] = Wq;  tw.dst[0] = WqT;  tw.cols[0] = 512;
  tw.src[1] = Wk;  tw.dst[1] = WkT;  tw.cols[1] = 512;
  tw.src[2] = Wv;  tw.dst[2] = WvT;  tw.cols[2] = 512;
  tw.src[3] = Wo;  tw.dst[3] = WoT;  tw.cols[3] = 512;
  tw.src[4] = Wc1;             tw.dst[4] = Wc1aT; tw.cols[4] = 256;
  tw.src[5] = Wc1 + 512 * 256; tw.dst[5] = Wc1bT; tw.cols[5] = 256;
  tw.src[6] = Wr1;             tw.dst[6] = Wr1aT; tw.cols[6] = 512;
  tw.src[7] = Wr1 + 512 * 512; tw.dst[7] = Wr1bT; tw.cols[7] = 512;
  hipLaunchKernelGGL(setup, dim3(8913), dim3(256), 0, stream, queries, convW,
                     Wproj, Wgate, rel_embed, bproj, br2, bgate, Wr2, tw, hbuf,
                     Qp, Wtb, crel, wrg, ccst);

  hipLaunchKernelGGL(conv_mfma, dim3(8, 25, 8), dim3(256), 0, stream, Qp, Wtb, hbuf);
  hipLaunchKernelGGL(bn_stats, dim3(512), dim3(256), 0, stream, hbuf, mu, rsg);
  hipLaunchKernelGGL(fuse_xs, dim3(3136), dim3(256), 0, stream, hbuf, mu, rsg,
                     queries, keys, values, eqh, ekh, evh);

  MJobs jb;
  for (int z = 0; z < 7; z++) jb.Ch[z] = nullptr;
  jb.A[0] = eqh; jb.BT[0] = WqT;   jb.bias[0] = bq;      jb.C[0] = qbuf; jb.N[0] = 512;
  jb.A[1] = ekh; jb.BT[1] = WkT;   jb.bias[1] = bk;      jb.C[1] = kbuf; jb.N[1] = 512;
  jb.A[2] = evh; jb.BT[2] = WvT;   jb.bias[2] = bv;      jb.C[2] = vbuf; jb.N[2] = 512;
  jb.A[3] = eqh; jb.BT[3] = Wc1aT; jb.bias[3] = bc1;     jb.C[3] = Cqw;  jb.N[3] = 256; jb.Ch[3] = Cqh;
  jb.A[4] = ekh; jb.BT[4] = Wc1bT; jb.bias[4] = nullptr; jb.C[4] = Ckw;  jb.N[4] = 256; jb.Ch[4] = Ckh;
  jb.A[5] = eqh; jb.BT[5] = Wr1aT; jb.bias[5] = br1;     jb.C[5] = Rqw;  jb.N[5] = 512; jb.Ch[5] = Rqh;
  jb.A[6] = ekh; jb.BT[6] = Wr1bT; jb.bias[6] = nullptr; jb.C[6] = Rkw;  jb.N[6] = 512; jb.Ch[6] = Rkh;
  hipLaunchKernelGGL(gemm_mf, dim3(8, 25, 7), dim3(256), 0, stream, jb);

  MidA ma;
  ma.rs_src[0] = Cqw; ma.rs_w[0] = 256;
  ma.rs_src[1] = Ckw; ma.rs_w[1] = 256;
  ma.rs_src[2] = Rqw; ma.rs_w[2] = 512;
  ma.rs_src[3] = Rkw; ma.rs_w[3] = 512;
  ma.t2_src[0] = Cqw; ma.t2_dst[0] = CqT2; ma.t2_C[0] = 256;
  ma.t2_src[1] = Ckw; ma.t2_dst[1] = CkT2; ma.t2_C[1] = 256;
  ma.t2_src[2] = Rqw; ma.t2_dst[2] = RqT2; ma.t2_C[2] = 512;
  ma.t2_src[3] = Rkw; ma.t2_dst[3] = RkT2; ma.t2_C[3] = 512;
  ma.gA[0] = Cqh; ma.gB[0] = Ckh; ma.gOut[0] = dotC; ma.gK[0] = 256;
  ma.gA[1] = Rqh; ma.gB[1] = Rkh; ma.gOut[1] = dotR; ma.gK[1] = 512;
  hipLaunchKernelGGL(mid, dim3(3984), dim3(256), 0, stream, ma, Ssum, SSsum);

  hipLaunchKernelGGL(pair_gate, dim3((NPAIR * 4 + 255) / 256), dim3(256), 0, stream,
                     CqT2, CkT2, RqT2, RkT2, Wc2, bc2, gc, bcln, gr, brln, crel,
                     wrg, ccst, Ssum, SSsum, dotC, dotR, gf);
  hipLaunchKernelGGL(attn, dim3(256), dim3(256), 0, stream, qbuf, kbuf, vbuf, gf, aoh);

  MJobs j2;
  for (int z = 0; z < 7; z++) {
    j2.A[z] = nullptr; j2.BT[z] = nullptr; j2.bias[z] = nullptr;
    j2.C[z] = nullptr; j2.Ch[z] = nullptr; j2.N[z] = 0;
  }
  j2.A[0] = aoh; j2.BT[0] = WoT; j2.bias[0] = bo; j2.C[0] = (float*)d_out; j2.N[0] = 512;
  hipLaunchKernelGGL(gemm_mf, dim3(8, 25, 1), dim3(256), 0, stream, j2);
}

// Round 9
// 314.573 us; speedup vs baseline: 1.1442x; 1.1087x over previous
//
#include <hip/hip_runtime.h>
#include <math.h>

typedef _Float16 f16;
typedef _Float16 f16x2 __attribute__((ext_vector_type(2)));
typedef _Float16 f16x8 __attribute__((ext_vector_type(8)));
typedef float f32x4 __attribute__((ext_vector_type(4)));

static constexpr int Mrows = 1568;   // 32*49
static constexpr int NPAIR = 76832;  // 32*49*49
static constexpr float SCALEC = 0.125f;
#define EPSV 1e-5f

// ---------- helpers ----------
__device__ inline float wsum(float v) {
#pragma unroll
  for (int m = 32; m >= 1; m >>= 1) v += __shfl_xor(v, m, 64);
  return v;
}
__device__ inline float wmax(float v) {
#pragma unroll
  for (int m = 32; m >= 1; m >>= 1) v = fmaxf(v, __shfl_xor(v, m, 64));
  return v;
}
__device__ inline void gld16(const void* g, void* l) {
  __builtin_amdgcn_global_load_lds((const __attribute__((address_space(1))) void*)g,
                                   (__attribute__((address_space(3))) void*)l, 16, 0, 0);
}
__device__ inline f16x2 H2(unsigned u) { return __builtin_bit_cast(f16x2, u); }
__device__ inline unsigned U32(f16x2 h) { return __builtin_bit_cast(unsigned, h); }
__device__ inline f16x2 pk2(float a, float b) {
  return __builtin_bit_cast(f16x2, __builtin_amdgcn_cvt_pkrtz(a, b));
}
__device__ inline float qsum(float v) {
  v += __shfl_xor(v, 1, 64);
  v += __shfl_xor(v, 2, 64);
  return v;
}

// ================= SETUP mega-kernel =================
// blocks [0,784): zero h | [784,5968): Qp | [5968,6992): Wtb
// [6992,8784): 8 weight transposes | [8784,8913): smalls (crel/wrg/cconst)
struct SetupW { const float* src[8]; f16* dst[8]; int cols[8]; };
__global__ __launch_bounds__(256) void setup(
    const float* __restrict__ queries, const float* __restrict__ convW,
    const float* __restrict__ Wproj, const float* __restrict__ Wgate,
    const float* __restrict__ rel_embed, const float* __restrict__ bproj,
    const float* __restrict__ br2, const float* __restrict__ bgate,
    const float* __restrict__ Wr2, SetupW tw, float* __restrict__ h,
    f16* __restrict__ Qp, f16* __restrict__ Wtb, float* __restrict__ crel,
    float* __restrict__ wrg, float* __restrict__ cconst) {
  __shared__ float tile[32][33];
  __shared__ float part[256];
  __shared__ float pgs[64];
  int bx = blockIdx.x;
  int tid = threadIdx.x;
  if (bx < 784) {
    ((float4*)h)[bx * 256 + tid] = make_float4(0.f, 0.f, 0.f, 0.f);
  } else if (bx < 5968) {
    int idx = (bx - 784) * 256 + tid;
    int c = idx & 511;
    int iijj = (idx >> 9) % 81;
    int b = idx / (81 * 512);
    int ii = iijj / 9, jj = iijj % 9;
    float v = 0.f;
    if (ii >= 1 && ii <= 7 && jj >= 1 && jj <= 7)
      v = queries[(((size_t)(b * 49 + (ii - 1) * 7 + (jj - 1))) << 9) + c];
    Qp[idx] = (f16)v;
  } else if (bx < 6992) {
    int idx = (bx - 5968) * 256 + tid;
    int o = idx >> 9, c = idx & 511;
    const float* s = convW + (size_t)o * 4608 + c * 9;
    f16* d = Wtb + (size_t)o * 4608 + c;
#pragma unroll
    for (int t = 0; t < 9; t++) d[t * 512] = (f16)s[t];
  } else if (bx < 8784) {
    // weight transpose+convert: dst[n][k] = (f16)src[k][n], K=512
    int l = bx - 6992;
    int z = 0;
    while (z < 8) {
      int nb = (tw.cols[z] >> 5) * 16;
      if (l < nb) break;
      l -= nb;
      z++;
    }
    int cols = tw.cols[z];
    int nx = cols >> 5;
    int n0 = (l % nx) * 32;
    int k0 = (l / nx) * 32;
    const float* src = tw.src[z];
    f16* dst = tw.dst[z];
    int c = tid & 31, r0 = tid >> 5;
#pragma unroll
    for (int i = 0; i < 4; i++) {
      int r = r0 + i * 8;
      tile[r][c] = src[(size_t)(k0 + r) * cols + n0 + c];
    }
    __syncthreads();
#pragma unroll
    for (int i = 0; i < 4; i++) {
      int r = r0 + i * 8;
      dst[(size_t)(n0 + r) * 512 + k0 + c] = (f16)tile[c][r];
    }
  } else {
    // smalls: crel[14], wrg[512], cconst — latency-optimized (full unroll, ILP)
    int l = bx - 8784;
    int wv = tid >> 6, lane = tid & 63;
    if (l == 0) {
      // pg[o] = Wproj[o,:]·Wgate : 4 threads per o, float4 fully unrolled
      int o = tid >> 2, pq = tid & 3;
      const float4* wp4 = (const float4*)(Wproj + (size_t)o * 512 + pq * 128);
      const float4* wg4 = (const float4*)(Wgate + pq * 128);
      float s = 0.f;
#pragma unroll
      for (int i = 0; i < 32; i++) {
        float4 a = wp4[i];
        float4 g = wg4[i];
        s += a.x * g.x + a.y * g.y + a.z * g.z + a.w * g.w;
      }
      part[tid] = s;
      __syncthreads();
      if (tid < 64)
        pgs[tid] = part[tid * 4] + part[tid * 4 + 1] + part[tid * 4 + 2] +
                   part[tid * 4 + 3];
      __syncthreads();
      if (tid < 14) {
        float s2 = 0.f;
#pragma unroll
        for (int dk = 0; dk < 64; dk++) s2 += rel_embed[tid * 64 + dk] * pgs[dk];
        crel[tid] = s2;
      }
      if (wv == 3) {
        float s3 = 0.f;
#pragma unroll
        for (int k2 = 0; k2 < 8; k2++) {
          int d = lane + k2 * 64;
          s3 += (bproj[d] + br2[d]) * Wgate[d];
        }
        s3 = wsum(s3);
        if (lane == 0) cconst[0] = s3 + bgate[0];
      }
    } else {
      int d = (l - 1) * 4 + wv;  // 128 blocks * 4 waves = 512
      const float* wr = Wr2 + (size_t)d * 512;
      float s = 0.f;
#pragma unroll
      for (int k2 = 0; k2 < 8; k2++) {
        int d2 = lane + k2 * 64;
        s += wr[d2] * Wgate[d2];
      }
      s = wsum(s);
      if (lane == 0) wrg[d] = s;
    }
  }
}

// ================= MID mega-kernel =================
// blocks [0,1568): row_sums | [1568,3920): t2h | [3920,3984): gram
struct MidA {
  const float* rs_src[4]; int rs_w[4];
  const float* t2_src[4]; unsigned* t2_dst[4]; int t2_C[4];
  const f16* gA[2]; const f16* gB[2]; float* gOut[2]; int gK[2];
};
__global__ __launch_bounds__(256) void mid(MidA ma, float* __restrict__ Ssum,
                                           float* __restrict__ SSsum) {
  __shared__ float tile[32][33];
  __shared__ f16 As2[2048];
  __shared__ f16 Bs2[2048];
  int bx = blockIdx.x;
  int tid = threadIdx.x;
  if (bx < 1568) {
    int j = bx / 392, xb = bx % 392;
    int w = ma.rs_w[j];
    const float* src = ma.rs_src[j];
    int row = xb * 4 + (tid >> 6);
    int lane = tid & 63;
    float s = 0.f, ss = 0.f;
    if (w == 256) {
#pragma unroll
      for (int k2 = 0; k2 < 4; k2++) {
        float v = src[(size_t)row * 256 + lane + k2 * 64];
        s += v;
        ss += v * v;
      }
    } else {
#pragma unroll
      for (int k2 = 0; k2 < 8; k2++) {
        float v = src[(size_t)row * 512 + lane + k2 * 64];
        s += v;
        ss += v * v;
      }
    }
    s = wsum(s);
    ss = wsum(ss);
    if (lane == 0) {
      Ssum[j * 1568 + row] = s;
      SSsum[j * 1568 + row] = ss;
    }
  } else if (bx < 3920) {
    int l = bx - 1568;
    int z = 0;
    while (z < 4) {
      int nb = (ma.t2_C[z] >> 5) * 49;
      if (l < nb) break;
      l -= nb;
      z++;
    }
    int C = ma.t2_C[z];
    int nx = C >> 5;
    int c0 = (l % nx) * 32;
    int r0 = (l / nx) * 32;
    const float* src = ma.t2_src[z];
    unsigned* dst = ma.t2_dst[z];
    int cc = tid & 31, rr = tid >> 5;
#pragma unroll
    for (int i = 0; i < 4; i++)
      tile[cc][rr + i * 8] = src[(size_t)(r0 + rr + i * 8) * C + c0 + cc];
    __syncthreads();
    int r = tid & 31, cp = tid >> 5;
#pragma unroll
    for (int i = 0; i < 2; i++) {
      int c = cp + i * 8;
      f16x2 p = pk2(tile[2 * c][r], tile[2 * c + 1][r]);
      dst[(size_t)((c0 >> 1) + c) * 1568 + r0 + r] = U32(p);
    }
  } else {
    // batched Gram via MFMA: out[b][q][k] = 2 * (A_row_q . B_row_k)
    int l = bx - 3920;
    int z = l >> 5, b = l & 31;
    int K = ma.gK[z];
    const f16* A = ma.gA[z] + (size_t)b * 49 * K;
    const f16* BT = ma.gB[z] + (size_t)b * 49 * K;
    float* out = ma.gOut[z] + (size_t)b * 2401;
    int lane = tid & 63, wv = tid >> 6;
    int kq = (tid >> 4) & 3, mm = tid & 15;
    int rowA = wv * 16 + mm;
    if (rowA > 48) rowA = 48;
    const f16* aSrc = A + (size_t)rowA * K + kq * 8;
    const f16* bSrc = BT + (size_t)rowA * K + kq * 8;
    f16* aDst = &As2[wv * 512];
    f16* bDst = &Bs2[wv * 512];
    f32x4 acc[4];
#pragma unroll
    for (int i = 0; i < 4; i++) acc[i] = (f32x4){0.f, 0.f, 0.f, 0.f};
    int steps = K >> 5;
    for (int s = 0; s < steps; s++) {
      gld16(aSrc + s * 32, aDst);
      gld16(bSrc + s * 32, bDst);
      __syncthreads();
      f16x8 a = *(const f16x8*)&As2[(wv << 9) + (lane << 3)];
#pragma unroll
      for (int nb = 0; nb < 4; nb++) {
        f16x8 bf = *(const f16x8*)&Bs2[(nb << 9) + (lane << 3)];
        acc[nb] = __builtin_amdgcn_mfma_f32_16x16x32_f16(a, bf, acc[nb], 0, 0, 0);
      }
      __syncthreads();
    }
    int r0 = wv * 16 + ((lane >> 4) << 2);
    int cw = lane & 15;
#pragma unroll
    for (int nb = 0; nb < 4; nb++) {
      int col = nb * 16 + cw;
#pragma unroll
      for (int r = 0; r < 4; r++) {
        int row = r0 + r;
        if (row < 49 && col < 49) out[row * 49 + col] = 2.f * acc[nb][r];
      }
    }
  }
}

// ---------- conv as implicit-im2col MFMA GEMM, split-K=8, atomicAdd into h ----------
__global__ __launch_bounds__(256) void conv_mfma(const f16* __restrict__ Qp,
                                                 const f16* __restrict__ Wtb,
                                                 float* __restrict__ h) {
  __shared__ f16 As2[2048];
  __shared__ f16 Bs2[2048];
  int tid = threadIdx.x;
  int n0 = blockIdx.x * 64;
  int m0 = blockIdx.y * 64;
  int kb = blockIdx.z * 576;
  int lane = tid & 63, wv = tid >> 6;
  int kq = (tid >> 4) & 3, mm = tid & 15;
  int rowA = m0 + wv * 16 + mm;
  if (rowA > Mrows - 1) rowA = Mrows - 1;
  int b = rowA / 49, p = rowA % 49;
  int pi = p / 7, pj = p % 7;
  const f16* qbase = Qp + (size_t)b * 81 * 512 + kq * 8;
  int rowB = n0 + wv * 16 + mm;
  const f16* bSrc = Wtb + (size_t)rowB * 4608 + kq * 8 + kb;
  f16* aDst = &As2[wv * 512];
  f16* bDst = &Bs2[wv * 512];
  f32x4 acc[4];
#pragma unroll
  for (int i = 0; i < 4; i++) acc[i] = (f32x4){0.f, 0.f, 0.f, 0.f};
  for (int s = 0; s < 18; s++) {
    int k0 = kb + s * 32;
    int t = k0 >> 9, c0 = k0 & 511;
    int ti = t / 3, tj = t - ti * 3;
    const f16* aSrc = qbase + (size_t)((pi + ti) * 9 + (pj + tj)) * 512 + c0;
    gld16(aSrc, aDst);
    gld16(bSrc + s * 32, bDst);
    __syncthreads();
    f16x8 a = *(const f16x8*)&As2[(wv << 9) + (lane << 3)];
#pragma unroll
    for (int nb = 0; nb < 4; nb++) {
      f16x8 bf = *(const f16x8*)&Bs2[(nb << 9) + (lane << 3)];
      acc[nb] = __builtin_amdgcn_mfma_f32_16x16x32_f16(a, bf, acc[nb], 0, 0, 0);
    }
    __syncthreads();
  }
  int r0 = m0 + wv * 16 + ((lane >> 4) << 2);
  int cw = lane & 15;
#pragma unroll
  for (int nb = 0; nb < 4; nb++) {
    int col = n0 + nb * 16 + cw;
#pragma unroll
    for (int r = 0; r < 4; r++) {
      int row = r0 + r;
      if (row < Mrows) atomicAdd(&h[(size_t)row * 512 + col], acc[nb][r]);
    }
  }
}

// ---------- BatchNorm stats per channel ----------
__global__ __launch_bounds__(256) void bn_stats(const float* __restrict__ h,
                                                float* __restrict__ mu,
                                                float* __restrict__ rsg) {
  int c = blockIdx.x;
  int tid = threadIdx.x;
  float s = 0.f, ss = 0.f;
#pragma unroll
  for (int k2 = 0; k2 < 7; k2++) {
    int r = tid + k2 * 256;
    if (r < Mrows) {
      float v = h[(size_t)r * 512 + c];
      s += v;
      ss += v * v;
    }
  }
  s = wsum(s);
  ss = wsum(ss);
  __shared__ float r1[4], r2[4];
  int wave = tid >> 6, lane = tid & 63;
  if (lane == 0) { r1[wave] = s; r2[wave] = ss; }
  __syncthreads();
  if (tid == 0) {
    float S = r1[0] + r1[1] + r1[2] + r1[3];
    float SS = r2[0] + r2[1] + r2[2] + r2[3];
    float m = S / (float)Mrows;
    float var = SS / (float)Mrows - m * m;
    mu[c] = m;
    rsg[c] = rsqrtf(var + EPSV);
  }
}

// ---------- xs = relu(bn(h)); eq/ek/ev (f16) ----------
__global__ __launch_bounds__(256) void fuse_xs(
    const float* __restrict__ h, const float* __restrict__ mu,
    const float* __restrict__ rsg, const float* __restrict__ Q,
    const float* __restrict__ Kin, const float* __restrict__ Vin,
    f16* __restrict__ eqh, f16* __restrict__ ekh, f16* __restrict__ evh) {
  int i = blockIdx.x * 256 + threadIdx.x;
  int c = i & 511;
  float xs = fmaxf((h[i] - mu[c]) * rsg[c], 0.f);
  eqh[i] = (f16)(xs + Q[i]);
  ekh[i] = (f16)(xs + Kin[i]);
  evh[i] = (f16)(xs + Vin[i]);
}

// ---------- generic MFMA GEMM (+optional f16 copy) ----------
struct MJobs {
  const f16* A[7]; const f16* BT[7]; const float* bias[7];
  float* C[7]; f16* Ch[7]; int N[7];
};
__global__ __launch_bounds__(256) void gemm_mf(MJobs jb) {
  int z = blockIdx.z;
  int N = jb.N[z];
  int n0 = blockIdx.x * 64;
  if (n0 >= N) return;
  int m0 = blockIdx.y * 64;
  const f16* A = jb.A[z];
  const f16* BT = jb.BT[z];
  __shared__ f16 As2[2048];
  __shared__ f16 Bs2[2048];
  int tid = threadIdx.x, lane = tid & 63, wv = tid >> 6;
  int kq = (tid >> 4) & 3, mm = tid & 15;
  int rowA = m0 + wv * 16 + mm;
  if (rowA > Mrows - 1) rowA = Mrows - 1;
  const f16* aSrc = A + (size_t)rowA * 512 + kq * 8;
  int rowB = n0 + wv * 16 + mm;
  const f16* bSrc = BT + (size_t)rowB * 512 + kq * 8;
  f16* aDst = &As2[wv * 512];
  f16* bDst = &Bs2[wv * 512];
  f32x4 acc[4];
#pragma unroll
  for (int i = 0; i < 4; i++) acc[i] = (f32x4){0.f, 0.f, 0.f, 0.f};
  for (int s = 0; s < 16; s++) {
    gld16(aSrc + s * 32, aDst);
    gld16(bSrc + s * 32, bDst);
    __syncthreads();
    f16x8 a = *(const f16x8*)&As2[(wv << 9) + (lane << 3)];
#pragma unroll
    for (int nb = 0; nb < 4; nb++) {
      f16x8 bf = *(const f16x8*)&Bs2[(nb << 9) + (lane << 3)];
      acc[nb] = __builtin_amdgcn_mfma_f32_16x16x32_f16(a, bf, acc[nb], 0, 0, 0);
    }
    __syncthreads();
  }
  const float* bias = jb.bias[z];
  float* C = jb.C[z];
  f16* Ch = jb.Ch[z];
  int r0 = m0 + wv * 16 + ((lane >> 4) << 2);
  int cw = lane & 15;
#pragma unroll
  for (int nb = 0; nb < 4; nb++) {
    int col = n0 + nb * 16 + cw;
    float bv = bias ? bias[col] : 0.f;
#pragma unroll
    for (int r = 0; r < 4; r++) {
      int row = r0 + r;
      if (row < Mrows) {
        float v = acc[nb][r] + bv;
        C[(size_t)row * N + col] = v;
        if (Ch) Ch[(size_t)row * N + col] = (f16)v;
      }
    }
  }
}

// ---------- pair gate: quad-per-pair, single pass (analytic LN stats) ----------
__global__ __launch_bounds__(256) void pair_gate(
    const unsigned* __restrict__ CqT, const unsigned* __restrict__ CkT,
    const unsigned* __restrict__ RqT, const unsigned* __restrict__ RkT,
    const float* __restrict__ Wc2, const float* __restrict__ bc2,
    const float* __restrict__ gc, const float* __restrict__ bcln,
    const float* __restrict__ gr, const float* __restrict__ brln,
    const float* __restrict__ crel, const float* __restrict__ wrg,
    const float* __restrict__ cconstp, const float* __restrict__ Ssum,
    const float* __restrict__ SSsum, const float* __restrict__ dotC,
    const float* __restrict__ dotR, float* __restrict__ gfac) {
  __shared__ uint4 sTC[512];
  __shared__ uint4 sTR[256];
  __shared__ float scl[14], sb2[14];
  int tid = threadIdx.x;
  if (tid < 128) {
    int dd = tid;
    unsigned w[16];
    w[0] = U32(pk2(gc[2 * dd], gc[2 * dd + 1]));
    w[1] = U32(pk2(bcln[2 * dd], bcln[2 * dd + 1]));
#pragma unroll
    for (int r = 0; r < 14; r++)
      w[2 + r] = U32(pk2(Wc2[(2 * dd) * 14 + r], Wc2[(2 * dd + 1) * 14 + r]));
#pragma unroll
    for (int j = 0; j < 4; j++)
      sTC[dd * 4 + j] = make_uint4(w[4 * j], w[4 * j + 1], w[4 * j + 2], w[4 * j + 3]);
  }
  {
    int dd = tid;
    sTR[dd] = make_uint4(U32(pk2(gr[2 * dd], gr[2 * dd + 1])),
                         U32(pk2(brln[2 * dd], brln[2 * dd + 1])),
                         U32(pk2(wrg[2 * dd], wrg[2 * dd + 1])), 0u);
  }
  if (tid < 14) { scl[tid] = crel[tid]; sb2[tid] = bc2[tid]; }
  __syncthreads();

  int gidx = blockIdx.x * 256 + tid;
  int pid = gidx >> 2;
  int sub = gidx & 3;
  bool valid = pid < NPAIR;
  int pc = valid ? pid : NPAIR - 1;
  int b = pc / 2401;
  int r2 = pc % 2401;
  int q = r2 / 49, k = r2 % 49;
  int rowq = b * 49 + q, rowk = b * 49 + k;
  const f16x2 zero2 = {(f16)0.f, (f16)0.f};

  float s1;
  {
    float sC = Ssum[rowq] + Ssum[1568 + rowk];
    float ssC = SSsum[rowq] + SSsum[1568 + rowk] + dotC[pc];
    float mC = sC * (1.f / 256.f);
    float var = ssC * (1.f / 256.f) - mC * mC;
    float rsC = rsqrtf(var + EPSV);
    f16x2 nm2 = pk2(-mC, -mC);
    f16x2 rs2 = pk2(rsC, rsC);

    float lg[14];
#pragma unroll
    for (int r = 0; r < 14; r++) lg[r] = 0.f;
    const unsigned* cq = CqT + (size_t)sub * 1568 + rowq;
    const unsigned* ck = CkT + (size_t)sub * 1568 + rowk;
#pragma unroll
    for (int j = 0; j < 32; j++) {
      int dd = 4 * j + sub;
      uint4 t0 = sTC[dd * 4 + 0];
      uint4 t1 = sTC[dd * 4 + 1];
      uint4 t2 = sTC[dd * 4 + 2];
      uint4 t3 = sTC[dd * 4 + 3];
      f16x2 z2 = H2(cq[(size_t)j * 4 * 1568]) + H2(ck[(size_t)j * 4 * 1568]);
      f16x2 u2 = (z2 + nm2) * rs2;
      f16x2 h2 = __builtin_elementwise_max(u2 * H2(t0.x) + H2(t0.y), zero2);
      lg[0] = __builtin_amdgcn_fdot2(h2, H2(t0.z), lg[0], false);
      lg[1] = __builtin_amdgcn_fdot2(h2, H2(t0.w), lg[1], false);
      lg[2] = __builtin_amdgcn_fdot2(h2, H2(t1.x), lg[2], false);
      lg[3] = __builtin_amdgcn_fdot2(h2, H2(t1.y), lg[3], false);
      lg[4] = __builtin_amdgcn_fdot2(h2, H2(t1.z), lg[4], false);
      lg[5] = __builtin_amdgcn_fdot2(h2, H2(t1.w), lg[5], false);
      lg[6] = __builtin_amdgcn_fdot2(h2, H2(t2.x), lg[6], false);
      lg[7] = __builtin_amdgcn_fdot2(h2, H2(t2.y), lg[7], false);
      lg[8] = __builtin_amdgcn_fdot2(h2, H2(t2.z), lg[8], false);
      lg[9] = __builtin_amdgcn_fdot2(h2, H2(t2.w), lg[9], false);
      lg[10] = __builtin_amdgcn_fdot2(h2, H2(t3.x), lg[10], false);
      lg[11] = __builtin_amdgcn_fdot2(h2, H2(t3.y), lg[11], false);
      lg[12] = __builtin_amdgcn_fdot2(h2, H2(t3.z), lg[12], false);
      lg[13] = __builtin_amdgcn_fdot2(h2, H2(t3.w), lg[13], false);
    }
#pragma unroll
    for (int r = 0; r < 14; r++) lg[r] = qsum(lg[r]) + sb2[r];

    float mx = lg[0];
#pragma unroll
    for (int r = 1; r < 14; r++) mx = fmaxf(mx, lg[r]);
    float se = 0.f, sc = 0.f;
#pragma unroll
    for (int r = 0; r < 14; r++) {
      float e = __expf(lg[r] - mx);
      se += e;
      sc += e * scl[r];
    }
    s1 = sc / (se * (1.f + 1e-8f));
  }

  float s2v;
  {
    float sR = Ssum[2 * 1568 + rowq] + Ssum[3 * 1568 + rowk];
    float ssR = SSsum[2 * 1568 + rowq] + SSsum[3 * 1568 + rowk] + dotR[pc];
    float mR = sR * (1.f / 512.f);
    float varR = ssR * (1.f / 512.f) - mR * mR;
    float rsR = rsqrtf(varR + EPSV);
    f16x2 nmR2 = pk2(-mR, -mR);
    f16x2 rsR2 = pk2(rsR, rsR);

    float acc = 0.f;
    const unsigned* rq = RqT + (size_t)sub * 1568 + rowq;
    const unsigned* rk = RkT + (size_t)sub * 1568 + rowk;
#pragma unroll
    for (int j = 0; j < 64; j++) {
      int dd = 4 * j + sub;
      uint4 tr = sTR[dd];
      f16x2 z2 = H2(rq[(size_t)j * 4 * 1568]) + H2(rk[(size_t)j * 4 * 1568]);
      f16x2 u2 = (z2 + nmR2) * rsR2;
      f16x2 h2 = __builtin_elementwise_max(u2 * H2(tr.x) + H2(tr.y), zero2);
      acc = __builtin_amdgcn_fdot2(h2, H2(tr.z), acc, false);
    }
    s2v = qsum(acc);
  }

  float gin = s1 + s2v + cconstp[0];
  float gate = 1.f / (1.f + __expf(-gin));
  if (valid && sub == 0) gfac[pid] = 1.f + gate;
}

// ---------- gated softmax attention, one block per (b,h); ao in f16 ----------
__global__ __launch_bounds__(256) void attn(const float* __restrict__ qb,
                                            const float* __restrict__ kb,
                                            const float* __restrict__ vb,
                                            const float* __restrict__ gfac,
                                            f16* __restrict__ aoh) {
  int b = blockIdx.x >> 3, h = blockIdx.x & 7;
  __shared__ float Kh[64][65];
  __shared__ float Vh[49][65];
  __shared__ float G[2401];
  int tid = threadIdx.x;
  for (int i = tid; i < 49 * 64; i += 256) {
    int k = i >> 6, d = i & 63;
    size_t off = (((size_t)(b * 49 + k)) << 9) + h * 64 + d;
    Kh[k][d] = kb[off];
    Vh[k][d] = vb[off];
  }
  for (int i = tid; i < 15 * 64; i += 256) {
    Kh[49 + (i >> 6)][i & 63] = 0.f;
  }
  for (int i = tid; i < 2401; i += 256) G[i] = gfac[b * 2401 + i];
  __syncthreads();
  int wave = tid >> 6, lane = tid & 63;
  for (int q = wave; q < 49; q += 4) {
    float qv = qb[(((size_t)(b * 49 + q)) << 9) + h * 64 + lane];
    float dot = 0.f;
#pragma unroll
    for (int d = 0; d < 64; d++) dot += __shfl(qv, d, 64) * Kh[lane][d];
    float enh = (lane < 49) ? dot * SCALEC * G[q * 49 + lane] : -1e30f;
    float mxv = wmax(enh);
    float e = (lane < 49) ? __expf(enh - mxv) : 0.f;
    float ssum = wsum(e);
    float w = e / ssum;
    float out = 0.f;
#pragma unroll
    for (int k = 0; k < 49; k++) out += __shfl(w, k, 64) * Vh[k][lane];
    aoh[(((size_t)(b * 49 + q)) << 9) + h * 64 + lane] = (f16)out;
  }
}

// ---------- launch ----------
extern "C" void kernel_launch(void* const* d_in, const int* in_sizes, int n_in,
                              void* d_out, int out_size, void* d_ws, size_t ws_size,
                              hipStream_t stream) {
  const float* queries = (const float*)d_in[0];
  const float* keys = (const float*)d_in[1];
  const float* values = (const float*)d_in[2];
  const float* Wq = (const float*)d_in[3];
  const float* bq = (const float*)d_in[4];
  const float* Wk = (const float*)d_in[5];
  const float* bk = (const float*)d_in[6];
  const float* Wv = (const float*)d_in[7];
  const float* bv = (const float*)d_in[8];
  const float* Wo = (const float*)d_in[9];
  const float* bo = (const float*)d_in[10];
  const float* rel_embed = (const float*)d_in[11];
  const float* Wproj = (const float*)d_in[12];
  const float* bproj = (const float*)d_in[13];
  const float* Wgate = (const float*)d_in[14];
  const float* bgate = (const float*)d_in[15];
  const float* Wc1 = (const float*)d_in[16];
  const float* bc1 = (const float*)d_in[17];
  const float* gc = (const float*)d_in[18];
  const float* bcln = (const float*)d_in[19];
  const float* Wc2 = (const float*)d_in[20];
  const float* bc2 = (const float*)d_in[21];
  const float* Wr1 = (const float*)d_in[22];
  const float* br1 = (const float*)d_in[23];
  const float* gr = (const float*)d_in[24];
  const float* brln = (const float*)d_in[25];
  const float* Wr2 = (const float*)d_in[26];
  const float* br2 = (const float*)d_in[27];
  const float* convW = (const float*)d_in[28];
  // d_in[29] = convb: cancelled by BatchNorm(affine=False)

  float* W = (float*)d_ws;
  size_t o = 0;
  f16* Qp = (f16*)(W + o); o += 663552;
  f16* Wtb = (f16*)(W + o); o += 1179648;
  f16* WqT = (f16*)(W + o); o += 131072;
  f16* WkT = (f16*)(W + o); o += 131072;
  f16* WvT = (f16*)(W + o); o += 131072;
  f16* WoT = (f16*)(W + o); o += 131072;
  f16* Wc1aT = (f16*)(W + o); o += 65536;
  f16* Wc1bT = (f16*)(W + o); o += 65536;
  f16* Wr1aT = (f16*)(W + o); o += 131072;
  f16* Wr1bT = (f16*)(W + o); o += 131072;
  float* hbuf = W + o; o += 802816;
  f16* eqh = (f16*)(W + o); o += 401408;
  f16* ekh = (f16*)(W + o); o += 401408;
  f16* evh = (f16*)(W + o); o += 401408;
  float* qbuf = W + o; o += 802816;
  float* kbuf = W + o; o += 802816;
  float* vbuf = W + o; o += 802816;
  float* Cqw = W + o; o += 401408;
  float* Ckw = W + o; o += 401408;
  float* Rqw = W + o; o += 802816;
  float* Rkw = W + o; o += 802816;
  f16* aoh = (f16*)(W + o); o += 200704;
  float* gf = W + o; o += 76832;
  float* mu = W + o; o += 512;
  float* rsg = W + o; o += 512;
  float* crel = W + o; o += 16;
  float* wrg = W + o; o += 512;
  float* ccst = W + o; o += 16;
  unsigned* CqT2 = (unsigned*)(W + o); o += 200704;  // [128][1568]
  unsigned* CkT2 = (unsigned*)(W + o); o += 200704;
  unsigned* RqT2 = (unsigned*)(W + o); o += 401408;  // [256][1568]
  unsigned* RkT2 = (unsigned*)(W + o); o += 401408;
  f16* Cqh = (f16*)(W + o); o += 200704;             // [1568][256] f16
  f16* Ckh = (f16*)(W + o); o += 200704;
  f16* Rqh = (f16*)(W + o); o += 401408;             // [1568][512] f16
  f16* Rkh = (f16*)(W + o); o += 401408;
  float* Ssum = W + o; o += 6272;                    // [4][1568]
  float* SSsum = W + o; o += 6272;
  float* dotC = W + o; o += 76832;
  float* dotR = W + o; o += 76832;

  SetupW tw;
  tw.src[0] = Wq;  tw.dst[0] = WqT;  tw.cols[0] = 512;
  tw.src[1] = Wk;  tw.dst[1] = WkT;  tw.cols[1] = 512;
  tw.src[2] = Wv;  tw.dst[2] = WvT;  tw.cols[2] = 512;
  tw.src[3] = Wo;  tw.dst[3] = WoT;  tw.cols[3] = 512;
  tw.src[4] = Wc1;             tw.dst[4] = Wc1aT; tw.cols[4] = 256;
  tw.src[5] = Wc1 + 512 * 256; tw.dst[5] = Wc1bT; tw.cols[5] = 256;
  tw.src[6] = Wr1;             tw.dst[6] = Wr1aT; tw.cols[6] = 512;
  tw.src[7] = Wr1 + 512 * 512; tw.dst[7] = Wr1bT; tw.cols[7] = 512;
  hipLaunchKernelGGL(setup, dim3(8913), dim3(256), 0, stream, queries, convW,
                     Wproj, Wgate, rel_embed, bproj, br2, bgate, Wr2, tw, hbuf,
                     Qp, Wtb, crel, wrg, ccst);

  hipLaunchKernelGGL(conv_mfma, dim3(8, 25, 8), dim3(256), 0, stream, Qp, Wtb, hbuf);
  hipLaunchKernelGGL(bn_stats, dim3(512), dim3(256), 0, stream, hbuf, mu, rsg);
  hipLaunchKernelGGL(fuse_xs, dim3(3136), dim3(256), 0, stream, hbuf, mu, rsg,
                     queries, keys, values, eqh, ekh, evh);

  MJobs jb;
  for (int z = 0; z < 7; z++) jb.Ch[z] = nullptr;
  jb.A[0] = eqh; jb.BT[0] = WqT;   jb.bias[0] = bq;      jb.C[0] = qbuf; jb.N[0] = 512;
  jb.A[1] = ekh; jb.BT[1] = WkT;   jb.bias[1] = bk;      jb.C[1] = kbuf; jb.N[1] = 512;
  jb.A[2] = evh; jb.BT[2] = WvT;   jb.bias[2] = bv;      jb.C[2] = vbuf; jb.N[2] = 512;
  jb.A[3] = eqh; jb.BT[3] = Wc1aT; jb.bias[3] = bc1;     jb.C[3] = Cqw;  jb.N[3] = 256; jb.Ch[3] = Cqh;
  jb.A[4] = ekh; jb.BT[4] = Wc1bT; jb.bias[4] = nullptr; jb.C[4] = Ckw;  jb.N[4] = 256; jb.Ch[4] = Ckh;
  jb.A[5] = eqh; jb.BT[5] = Wr1aT; jb.bias[5] = br1;     jb.C[5] = Rqw;  jb.N[5] = 512; jb.Ch[5] = Rqh;
  jb.A[6] = ekh; jb.BT[6] = Wr1bT; jb.bias[6] = nullptr; jb.C[6] = Rkw;  jb.N[6] = 512; jb.Ch[6] = Rkh;
  hipLaunchKernelGGL(gemm_mf, dim3(8, 25, 7), dim3(256), 0, stream, jb);

  MidA ma;
  ma.rs_src[0] = Cqw; ma.rs_w[0] = 256;
  ma.rs_src[1] = Ckw; ma.rs_w[1] = 256;
  ma.rs_src[2] = Rqw; ma.rs_w[2] = 512;
  ma.rs_src[3] = Rkw; ma.rs_w[3] = 512;
  ma.t2_src[0] = Cqw; ma.t2_dst[0] = CqT2; ma.t2_C[0] = 256;
  ma.t2_src[1] = Ckw; ma.t2_dst[1] = CkT2; ma.t2_C[1] = 256;
  ma.t2_src[2] = Rqw; ma.t2_dst[2] = RqT2; ma.t2_C[2] = 512;
  ma.t2_src[3] = Rkw; ma.t2_dst[3] = RkT2; ma.t2_C[3] = 512;
  ma.gA[0] = Cqh; ma.gB[0] = Ckh; ma.gOut[0] = dotC; ma.gK[0] = 256;
  ma.gA[1] = Rqh; ma.gB[1] = Rkh; ma.gOut[1] = dotR; ma.gK[1] = 512;
  hipLaunchKernelGGL(mid, dim3(3984), dim3(256), 0, stream, ma, Ssum, SSsum);

  hipLaunchKernelGGL(pair_gate, dim3((NPAIR * 4 + 255) / 256), dim3(256), 0, stream,
                     CqT2, CkT2, RqT2, RkT2, Wc2, bc2, gc, bcln, gr, brln, crel,
                     wrg, ccst, Ssum, SSsum, dotC, dotR, gf);
  hipLaunchKernelGGL(attn, dim3(256), dim3(256), 0, stream, qbuf, kbuf, vbuf, gf, aoh);

  MJobs j2;
  for (int z = 0; z < 7; z++) {
    j2.A[z] = nullptr; j2.BT[z] = nullptr; j2.bias[z] = nullptr;
    j2.C[z] = nullptr; j2.Ch[z] = nullptr; j2.N[z] = 0;
  }
  j2.A[0] = aoh; j2.BT[0] = WoT; j2.bias[0] = bo; j2.C[0] = (float*)d_out; j2.N[0] = 512;
  hipLaunchKernelGGL(gemm_mf, dim3(8, 25, 1), dim3(256), 0, stream, j2);
}

// Round 11
// 305.186 us; speedup vs baseline: 1.1794x; 1.0308x over previous
//
#include <hip/hip_runtime.h>
#include <math.h>

typedef _Float16 f16;
typedef _Float16 f16x2 __attribute__((ext_vector_type(2)));
typedef _Float16 f16x8 __attribute__((ext_vector_type(8)));
typedef float f32x4 __attribute__((ext_vector_type(4)));

static constexpr int Mrows = 1568;   // 32*49
static constexpr int NPAIR = 76832;  // 32*49*49
static constexpr float SCALEC = 0.125f;
#define EPSV 1e-5f

// ---------- helpers ----------
__device__ inline float wsum(float v) {
#pragma unroll
  for (int m = 32; m >= 1; m >>= 1) v += __shfl_xor(v, m, 64);
  return v;
}
__device__ inline float wmax(float v) {
#pragma unroll
  for (int m = 32; m >= 1; m >>= 1) v = fmaxf(v, __shfl_xor(v, m, 64));
  return v;
}
__device__ inline void gld16(const void* g, void* l) {
  __builtin_amdgcn_global_load_lds((const __attribute__((address_space(1))) void*)g,
                                   (__attribute__((address_space(3))) void*)l, 16, 0, 0);
}
__device__ inline f16x2 H2(unsigned u) { return __builtin_bit_cast(f16x2, u); }
__device__ inline unsigned U32(f16x2 h) { return __builtin_bit_cast(unsigned, h); }
__device__ inline f16x2 pk2(float a, float b) {
  return __builtin_bit_cast(f16x2, __builtin_amdgcn_cvt_pkrtz(a, b));
}
__device__ inline float qsum(float v) {
  v += __shfl_xor(v, 1, 64);
  v += __shfl_xor(v, 2, 64);
  return v;
}

// ================= SETUP mega-kernel =================
// blocks [0,784): zero h | [784,5968): Qp | [5968,6992): Wtb
// [6992,8784): 8 weight transposes | [8784,8913): smalls (crel/wrg/cconst)
struct SetupW { const float* src[8]; f16* dst[8]; int cols[8]; };
__global__ __launch_bounds__(256) void setup(
    const float* __restrict__ queries, const float* __restrict__ convW,
    const float* __restrict__ Wproj, const float* __restrict__ Wgate,
    const float* __restrict__ rel_embed, const float* __restrict__ bproj,
    const float* __restrict__ br2, const float* __restrict__ bgate,
    const float* __restrict__ Wr2, SetupW tw, float* __restrict__ h,
    f16* __restrict__ Qp, f16* __restrict__ Wtb, float* __restrict__ crel,
    float* __restrict__ wrg, float* __restrict__ cconst) {
  __shared__ float tile[32][33];
  __shared__ float part[256];
  __shared__ float pgs[64];
  int bx = blockIdx.x;
  int tid = threadIdx.x;
  if (bx < 784) {
    ((float4*)h)[bx * 256 + tid] = make_float4(0.f, 0.f, 0.f, 0.f);
  } else if (bx < 5968) {
    int idx = (bx - 784) * 256 + tid;
    int c = idx & 511;
    int iijj = (idx >> 9) % 81;
    int b = idx / (81 * 512);
    int ii = iijj / 9, jj = iijj % 9;
    float v = 0.f;
    if (ii >= 1 && ii <= 7 && jj >= 1 && jj <= 7)
      v = queries[(((size_t)(b * 49 + (ii - 1) * 7 + (jj - 1))) << 9) + c];
    Qp[idx] = (f16)v;
  } else if (bx < 6992) {
    int idx = (bx - 5968) * 256 + tid;
    int o = idx >> 9, c = idx & 511;
    const float* s = convW + (size_t)o * 4608 + c * 9;
    f16* d = Wtb + (size_t)o * 4608 + c;
#pragma unroll
    for (int t = 0; t < 9; t++) d[t * 512] = (f16)s[t];
  } else if (bx < 8784) {
    // weight transpose+convert: dst[n][k] = (f16)src[k][n], K=512
    int l = bx - 6992;
    int z = 0;
    while (z < 8) {
      int nb = (tw.cols[z] >> 5) * 16;
      if (l < nb) break;
      l -= nb;
      z++;
    }
    int cols = tw.cols[z];
    int nx = cols >> 5;
    int n0 = (l % nx) * 32;
    int k0 = (l / nx) * 32;
    const float* src = tw.src[z];
    f16* dst = tw.dst[z];
    int c = tid & 31, r0 = tid >> 5;
#pragma unroll
    for (int i = 0; i < 4; i++) {
      int r = r0 + i * 8;
      tile[r][c] = src[(size_t)(k0 + r) * cols + n0 + c];
    }
    __syncthreads();
#pragma unroll
    for (int i = 0; i < 4; i++) {
      int r = r0 + i * 8;
      dst[(size_t)(n0 + r) * 512 + k0 + c] = (f16)tile[c][r];
    }
  } else {
    // smalls: crel[14], wrg[512], cconst — latency-optimized (full unroll, ILP)
    int l = bx - 8784;
    int wv = tid >> 6, lane = tid & 63;
    if (l == 0) {
      int o = tid >> 2, pq = tid & 3;
      const float4* wp4 = (const float4*)(Wproj + (size_t)o * 512 + pq * 128);
      const float4* wg4 = (const float4*)(Wgate + pq * 128);
      float s = 0.f;
#pragma unroll
      for (int i = 0; i < 32; i++) {
        float4 a = wp4[i];
        float4 g = wg4[i];
        s += a.x * g.x + a.y * g.y + a.z * g.z + a.w * g.w;
      }
      part[tid] = s;
      __syncthreads();
      if (tid < 64)
        pgs[tid] = part[tid * 4] + part[tid * 4 + 1] + part[tid * 4 + 2] +
                   part[tid * 4 + 3];
      __syncthreads();
      if (tid < 14) {
        float s2 = 0.f;
#pragma unroll
        for (int dk = 0; dk < 64; dk++) s2 += rel_embed[tid * 64 + dk] * pgs[dk];
        crel[tid] = s2;
      }
      if (wv == 3) {
        float s3 = 0.f;
#pragma unroll
        for (int k2 = 0; k2 < 8; k2++) {
          int d = lane + k2 * 64;
          s3 += (bproj[d] + br2[d]) * Wgate[d];
        }
        s3 = wsum(s3);
        if (lane == 0) cconst[0] = s3 + bgate[0];
      }
    } else {
      int d = (l - 1) * 4 + wv;  // 128 blocks * 4 waves = 512
      const float* wr = Wr2 + (size_t)d * 512;
      float s = 0.f;
#pragma unroll
      for (int k2 = 0; k2 < 8; k2++) {
        int d2 = lane + k2 * 64;
        s += wr[d2] * Wgate[d2];
      }
      s = wsum(s);
      if (lane == 0) wrg[d] = s;
    }
  }
}

// ================= MID mega-kernel =================
// blocks [0,1568): row_sums | [1568,3920): t2h | [3920,3984): gram
struct MidA {
  const float* rs_src[4]; int rs_w[4];
  const float* t2_src[4]; unsigned* t2_dst[4]; int t2_C[4];
  const f16* gA[2]; const f16* gB[2]; float* gOut[2]; int gK[2];
};
__global__ __launch_bounds__(256) void mid(MidA ma, float* __restrict__ Ssum,
                                           float* __restrict__ SSsum) {
  __shared__ float tile[32][33];
  __shared__ f16 As2[2048];
  __shared__ f16 Bs2[2048];
  int bx = blockIdx.x;
  int tid = threadIdx.x;
  if (bx < 1568) {
    int j = bx / 392, xb = bx % 392;
    int w = ma.rs_w[j];
    const float* src = ma.rs_src[j];
    int row = xb * 4 + (tid >> 6);
    int lane = tid & 63;
    float s = 0.f, ss = 0.f;
    if (w == 256) {
#pragma unroll
      for (int k2 = 0; k2 < 4; k2++) {
        float v = src[(size_t)row * 256 + lane + k2 * 64];
        s += v;
        ss += v * v;
      }
    } else {
#pragma unroll
      for (int k2 = 0; k2 < 8; k2++) {
        float v = src[(size_t)row * 512 + lane + k2 * 64];
        s += v;
        ss += v * v;
      }
    }
    s = wsum(s);
    ss = wsum(ss);
    if (lane == 0) {
      Ssum[j * 1568 + row] = s;
      SSsum[j * 1568 + row] = ss;
    }
  } else if (bx < 3920) {
    int l = bx - 1568;
    int z = 0;
    while (z < 4) {
      int nb = (ma.t2_C[z] >> 5) * 49;
      if (l < nb) break;
      l -= nb;
      z++;
    }
    int C = ma.t2_C[z];
    int nx = C >> 5;
    int c0 = (l % nx) * 32;
    int r0 = (l / nx) * 32;
    const float* src = ma.t2_src[z];
    unsigned* dst = ma.t2_dst[z];
    int cc = tid & 31, rr = tid >> 5;
#pragma unroll
    for (int i = 0; i < 4; i++)
      tile[cc][rr + i * 8] = src[(size_t)(r0 + rr + i * 8) * C + c0 + cc];
    __syncthreads();
    int r = tid & 31, cp = tid >> 5;
#pragma unroll
    for (int i = 0; i < 2; i++) {
      int c = cp + i * 8;
      f16x2 p = pk2(tile[2 * c][r], tile[2 * c + 1][r]);
      dst[(size_t)((c0 >> 1) + c) * 1568 + r0 + r] = U32(p);
    }
  } else {
    // batched Gram via MFMA: out[b][q][k] = 2 * (A_row_q . B_row_k)
    int l = bx - 3920;
    int z = l >> 5, b = l & 31;
    int K = ma.gK[z];
    const f16* A = ma.gA[z] + (size_t)b * 49 * K;
    const f16* BT = ma.gB[z] + (size_t)b * 49 * K;
    float* out = ma.gOut[z] + (size_t)b * 2401;
    int lane = tid & 63, wv = tid >> 6;
    int kq = (tid >> 4) & 3, mm = tid & 15;
    int rowA = wv * 16 + mm;
    if (rowA > 48) rowA = 48;
    const f16* aSrc = A + (size_t)rowA * K + kq * 8;
    const f16* bSrc = BT + (size_t)rowA * K + kq * 8;
    f16* aDst = &As2[wv * 512];
    f16* bDst = &Bs2[wv * 512];
    f32x4 acc[4];
#pragma unroll
    for (int i = 0; i < 4; i++) acc[i] = (f32x4){0.f, 0.f, 0.f, 0.f};
    int steps = K >> 5;
    for (int s = 0; s < steps; s++) {
      gld16(aSrc + s * 32, aDst);
      gld16(bSrc + s * 32, bDst);
      __syncthreads();
      f16x8 a = *(const f16x8*)&As2[(wv << 9) + (lane << 3)];
#pragma unroll
      for (int nb = 0; nb < 4; nb++) {
        f16x8 bf = *(const f16x8*)&Bs2[(nb << 9) + (lane << 3)];
        acc[nb] = __builtin_amdgcn_mfma_f32_16x16x32_f16(a, bf, acc[nb], 0, 0, 0);
      }
      __syncthreads();
    }
    int r0 = wv * 16 + ((lane >> 4) << 2);
    int cw = lane & 15;
#pragma unroll
    for (int nb = 0; nb < 4; nb++) {
      int col = nb * 16 + cw;
#pragma unroll
      for (int r = 0; r < 4; r++) {
        int row = r0 + r;
        if (row < 49 && col < 49) out[row * 49 + col] = 2.f * acc[nb][r];
      }
    }
  }
}

// ---------- conv: implicit-im2col MFMA GEMM, BK=64, split-K=4, atomicAdd ----------
__global__ __launch_bounds__(256) void conv_mfma(const f16* __restrict__ Qp,
                                                 const f16* __restrict__ Wtb,
                                                 float* __restrict__ h) {
  __shared__ f16 As2[4096];  // [wv][kk2][kq][mm][8]
  __shared__ f16 Bs2[4096];
  int tid = threadIdx.x;
  int n0 = blockIdx.x * 64;
  int m0 = blockIdx.y * 64;
  int kb = blockIdx.z * 1152;  // 4 slices x 1152 = 4608; 1152 = 18*64, 64 | 512
  int lane = tid & 63, wv = tid >> 6;
  int kq = (tid >> 4) & 3, mm = tid & 15;
  int rowA = m0 + wv * 16 + mm;
  if (rowA > Mrows - 1) rowA = Mrows - 1;
  int b = rowA / 49, p = rowA % 49;
  int pi = p / 7, pj = p % 7;
  const f16* qbase = Qp + (size_t)b * 81 * 512 + kq * 8;
  int rowB = n0 + wv * 16 + mm;
  const f16* bSrc = Wtb + (size_t)rowB * 4608 + kq * 8 + kb;
  f16* aDst0 = &As2[wv * 1024];
  f16* aDst1 = &As2[wv * 1024 + 512];
  f16* bDst0 = &Bs2[wv * 1024];
  f16* bDst1 = &Bs2[wv * 1024 + 512];
  f32x4 acc[4];
#pragma unroll
  for (int i = 0; i < 4; i++) acc[i] = (f32x4){0.f, 0.f, 0.f, 0.f};
  for (int s = 0; s < 18; s++) {
    int k0 = kb + s * 64;
    int t = k0 >> 9, c0 = k0 & 511;  // k0 is a multiple of 64 -> never crosses a tap
    int ti = t / 3, tj = t - ti * 3;
    const f16* aSrc = qbase + (size_t)((pi + ti) * 9 + (pj + tj)) * 512 + c0;
    gld16(aSrc, aDst0);
    gld16(aSrc + 32, aDst1);
    gld16(bSrc + s * 64, bDst0);
    gld16(bSrc + s * 64 + 32, bDst1);
    __syncthreads();
#pragma unroll
    for (int kk = 0; kk < 2; kk++) {
      f16x8 a = *(const f16x8*)&As2[wv * 1024 + kk * 512 + lane * 8];
#pragma unroll
      for (int nb = 0; nb < 4; nb++) {
        f16x8 bf = *(const f16x8*)&Bs2[nb * 1024 + kk * 512 + lane * 8];
        acc[nb] = __builtin_amdgcn_mfma_f32_16x16x32_f16(a, bf, acc[nb], 0, 0, 0);
      }
    }
    __syncthreads();
  }
  int r0 = m0 + wv * 16 + ((lane >> 4) << 2);
  int cw = lane & 15;
#pragma unroll
  for (int nb = 0; nb < 4; nb++) {
    int col = n0 + nb * 16 + cw;
#pragma unroll
    for (int r = 0; r < 4; r++) {
      int row = r0 + r;
      if (row < Mrows) atomicAdd(&h[(size_t)row * 512 + col], acc[nb][r]);
    }
  }
}

// ---------- BatchNorm stats per channel ----------
__global__ __launch_bounds__(256) void bn_stats(const float* __restrict__ h,
                                                float* __restrict__ mu,
                                                float* __restrict__ rsg) {
  int c = blockIdx.x;
  int tid = threadIdx.x;
  float s = 0.f, ss = 0.f;
#pragma unroll
  for (int k2 = 0; k2 < 7; k2++) {
    int r = tid + k2 * 256;
    if (r < Mrows) {
      float v = h[(size_t)r * 512 + c];
      s += v;
      ss += v * v;
    }
  }
  s = wsum(s);
  ss = wsum(ss);
  __shared__ float r1[4], r2[4];
  int wave = tid >> 6, lane = tid & 63;
  if (lane == 0) { r1[wave] = s; r2[wave] = ss; }
  __syncthreads();
  if (tid == 0) {
    float S = r1[0] + r1[1] + r1[2] + r1[3];
    float SS = r2[0] + r2[1] + r2[2] + r2[3];
    float m = S / (float)Mrows;
    float var = SS / (float)Mrows - m * m;
    mu[c] = m;
    rsg[c] = rsqrtf(var + EPSV);
  }
}

// ---------- xs = relu(bn(h)); eq/ek/ev (f16) ----------
__global__ __launch_bounds__(256) void fuse_xs(
    const float* __restrict__ h, const float* __restrict__ mu,
    const float* __restrict__ rsg, const float* __restrict__ Q,
    const float* __restrict__ Kin, const float* __restrict__ Vin,
    f16* __restrict__ eqh, f16* __restrict__ ekh, f16* __restrict__ evh) {
  int i = blockIdx.x * 256 + threadIdx.x;
  int c = i & 511;
  float xs = fmaxf((h[i] - mu[c]) * rsg[c], 0.f);
  eqh[i] = (f16)(xs + Q[i]);
  ekh[i] = (f16)(xs + Kin[i]);
  evh[i] = (f16)(xs + Vin[i]);
}

// ---------- generic MFMA GEMM (+optional f16 copy) ----------
struct MJobs {
  const f16* A[7]; const f16* BT[7]; const float* bias[7];
  float* C[7]; f16* Ch[7]; int N[7];
};
__global__ __launch_bounds__(256) void gemm_mf(MJobs jb) {
  int z = blockIdx.z;
  int N = jb.N[z];
  int n0 = blockIdx.x * 64;
  if (n0 >= N) return;
  int m0 = blockIdx.y * 64;
  const f16* A = jb.A[z];
  const f16* BT = jb.BT[z];
  __shared__ f16 As2[2048];
  __shared__ f16 Bs2[2048];
  int tid = threadIdx.x, lane = tid & 63, wv = tid >> 6;
  int kq = (tid >> 4) & 3, mm = tid & 15;
  int rowA = m0 + wv * 16 + mm;
  if (rowA > Mrows - 1) rowA = Mrows - 1;
  const f16* aSrc = A + (size_t)rowA * 512 + kq * 8;
  int rowB = n0 + wv * 16 + mm;
  const f16* bSrc = BT + (size_t)rowB * 512 + kq * 8;
  f16* aDst = &As2[wv * 512];
  f16* bDst = &Bs2[wv * 512];
  f32x4 acc[4];
#pragma unroll
  for (int i = 0; i < 4; i++) acc[i] = (f32x4){0.f, 0.f, 0.f, 0.f};
  for (int s = 0; s < 16; s++) {
    gld16(aSrc + s * 32, aDst);
    gld16(bSrc + s * 32, bDst);
    __syncthreads();
    f16x8 a = *(const f16x8*)&As2[(wv << 9) + (lane << 3)];
#pragma unroll
    for (int nb = 0; nb < 4; nb++) {
      f16x8 bf = *(const f16x8*)&Bs2[(nb << 9) + (lane << 3)];
      acc[nb] = __builtin_amdgcn_mfma_f32_16x16x32_f16(a, bf, acc[nb], 0, 0, 0);
    }
    __syncthreads();
  }
  const float* bias = jb.bias[z];
  float* C = jb.C[z];
  f16* Ch = jb.Ch[z];
  int r0 = m0 + wv * 16 + ((lane >> 4) << 2);
  int cw = lane & 15;
#pragma unroll
  for (int nb = 0; nb < 4; nb++) {
    int col = n0 + nb * 16 + cw;
    float bv = bias ? bias[col] : 0.f;
#pragma unroll
    for (int r = 0; r < 4; r++) {
      int row = r0 + r;
      if (row < Mrows) {
        float v = acc[nb][r] + bv;
        C[(size_t)row * N + col] = v;
        if (Ch) Ch[(size_t)row * N + col] = (f16)v;
      }
    }
  }
}

// ---------- pair gate: quad-per-pair, single pass (analytic LN stats) ----------
__global__ __launch_bounds__(256) void pair_gate(
    const unsigned* __restrict__ CqT, const unsigned* __restrict__ CkT,
    const unsigned* __restrict__ RqT, const unsigned* __restrict__ RkT,
    const float* __restrict__ Wc2, const float* __restrict__ bc2,
    const float* __restrict__ gc, const float* __restrict__ bcln,
    const float* __restrict__ gr, const float* __restrict__ brln,
    const float* __restrict__ crel, const float* __restrict__ wrg,
    const float* __restrict__ cconstp, const float* __restrict__ Ssum,
    const float* __restrict__ SSsum, const float* __restrict__ dotC,
    const float* __restrict__ dotR, float* __restrict__ gfac) {
  __shared__ uint4 sTC[512];
  __shared__ uint4 sTR[256];
  __shared__ float scl[14], sb2[14];
  int tid = threadIdx.x;
  if (tid < 128) {
    int dd = tid;
    unsigned w[16];
    w[0] = U32(pk2(gc[2 * dd], gc[2 * dd + 1]));
    w[1] = U32(pk2(bcln[2 * dd], bcln[2 * dd + 1]));
#pragma unroll
    for (int r = 0; r < 14; r++)
      w[2 + r] = U32(pk2(Wc2[(2 * dd) * 14 + r], Wc2[(2 * dd + 1) * 14 + r]));
#pragma unroll
    for (int j = 0; j < 4; j++)
      sTC[dd * 4 + j] = make_uint4(w[4 * j], w[4 * j + 1], w[4 * j + 2], w[4 * j + 3]);
  }
  {
    int dd = tid;
    sTR[dd] = make_uint4(U32(pk2(gr[2 * dd], gr[2 * dd + 1])),
                         U32(pk2(brln[2 * dd], brln[2 * dd + 1])),
                         U32(pk2(wrg[2 * dd], wrg[2 * dd + 1])), 0u);
  }
  if (tid < 14) { scl[tid] = crel[tid]; sb2[tid] = bc2[tid]; }
  __syncthreads();

  int gidx = blockIdx.x * 256 + tid;
  int pid = gidx >> 2;
  int sub = gidx & 3;
  bool valid = pid < NPAIR;
  int pc = valid ? pid : NPAIR - 1;
  int b = pc / 2401;
  int r2 = pc % 2401;
  int q = r2 / 49, k = r2 % 49;
  int rowq = b * 49 + q, rowk = b * 49 + k;
  const f16x2 zero2 = {(f16)0.f, (f16)0.f};

  float s1;
  {
    float sC = Ssum[rowq] + Ssum[1568 + rowk];
    float ssC = SSsum[rowq] + SSsum[1568 + rowk] + dotC[pc];
    float mC = sC * (1.f / 256.f);
    float var = ssC * (1.f / 256.f) - mC * mC;
    float rsC = rsqrtf(var + EPSV);
    f16x2 nm2 = pk2(-mC, -mC);
    f16x2 rs2 = pk2(rsC, rsC);

    float lg[14];
#pragma unroll
    for (int r = 0; r < 14; r++) lg[r] = 0.f;
    const unsigned* cq = CqT + (size_t)sub * 1568 + rowq;
    const unsigned* ck = CkT + (size_t)sub * 1568 + rowk;
#pragma unroll
    for (int j = 0; j < 32; j++) {
      int dd = 4 * j + sub;
      uint4 t0 = sTC[dd * 4 + 0];
      uint4 t1 = sTC[dd * 4 + 1];
      uint4 t2 = sTC[dd * 4 + 2];
      uint4 t3 = sTC[dd * 4 + 3];
      f16x2 z2 = H2(cq[(size_t)j * 4 * 1568]) + H2(ck[(size_t)j * 4 * 1568]);
      f16x2 u2 = (z2 + nm2) * rs2;
      f16x2 h2 = __builtin_elementwise_max(u2 * H2(t0.x) + H2(t0.y), zero2);
      lg[0] = __builtin_amdgcn_fdot2(h2, H2(t0.z), lg[0], false);
      lg[1] = __builtin_amdgcn_fdot2(h2, H2(t0.w), lg[1], false);
      lg[2] = __builtin_amdgcn_fdot2(h2, H2(t1.x), lg[2], false);
      lg[3] = __builtin_amdgcn_fdot2(h2, H2(t1.y), lg[3], false);
      lg[4] = __builtin_amdgcn_fdot2(h2, H2(t1.z), lg[4], false);
      lg[5] = __builtin_amdgcn_fdot2(h2, H2(t1.w), lg[5], false);
      lg[6] = __builtin_amdgcn_fdot2(h2, H2(t2.x), lg[6], false);
      lg[7] = __builtin_amdgcn_fdot2(h2, H2(t2.y), lg[7], false);
      lg[8] = __builtin_amdgcn_fdot2(h2, H2(t2.z), lg[8], false);
      lg[9] = __builtin_amdgcn_fdot2(h2, H2(t2.w), lg[9], false);
      lg[10] = __builtin_amdgcn_fdot2(h2, H2(t3.x), lg[10], false);
      lg[11] = __builtin_amdgcn_fdot2(h2, H2(t3.y), lg[11], false);
      lg[12] = __builtin_amdgcn_fdot2(h2, H2(t3.z), lg[12], false);
      lg[13] = __builtin_amdgcn_fdot2(h2, H2(t3.w), lg[13], false);
    }
#pragma unroll
    for (int r = 0; r < 14; r++) lg[r] = qsum(lg[r]) + sb2[r];

    float mx = lg[0];
#pragma unroll
    for (int r = 1; r < 14; r++) mx = fmaxf(mx, lg[r]);
    float se = 0.f, sc = 0.f;
#pragma unroll
    for (int r = 0; r < 14; r++) {
      float e = __expf(lg[r] - mx);
      se += e;
      sc += e * scl[r];
    }
    s1 = sc / (se * (1.f + 1e-8f));
  }

  float s2v;
  {
    float sR = Ssum[2 * 1568 + rowq] + Ssum[3 * 1568 + rowk];
    float ssR = SSsum[2 * 1568 + rowq] + SSsum[3 * 1568 + rowk] + dotR[pc];
    float mR = sR * (1.f / 512.f);
    float varR = ssR * (1.f / 512.f) - mR * mR;
    float rsR = rsqrtf(varR + EPSV);
    f16x2 nmR2 = pk2(-mR, -mR);
    f16x2 rsR2 = pk2(rsR, rsR);

    float acc = 0.f;
    const unsigned* rq = RqT + (size_t)sub * 1568 + rowq;
    const unsigned* rk = RkT + (size_t)sub * 1568 + rowk;
#pragma unroll
    for (int j = 0; j < 64; j++) {
      int dd = 4 * j + sub;
      uint4 tr = sTR[dd];
      f16x2 z2 = H2(rq[(size_t)j * 4 * 1568]) + H2(rk[(size_t)j * 4 * 1568]);
      f16x2 u2 = (z2 + nmR2) * rsR2;
      f16x2 h2 = __builtin_elementwise_max(u2 * H2(tr.x) + H2(tr.y), zero2);
      acc = __builtin_amdgcn_fdot2(h2, H2(tr.z), acc, false);
    }
    s2v = qsum(acc);
  }

  float gin = s1 + s2v + cconstp[0];
  float gate = 1.f / (1.f + __expf(-gin));
  if (valid && sub == 0) gfac[pid] = 1.f + gate;
}

// ---------- gated softmax attention, one block per (b,h); ao in f16 ----------
__global__ __launch_bounds__(256) void attn(const float* __restrict__ qb,
                                            const float* __restrict__ kb,
                                            const float* __restrict__ vb,
                                            const float* __restrict__ gfac,
                                            f16* __restrict__ aoh) {
  int b = blockIdx.x >> 3, h = blockIdx.x & 7;
  __shared__ float Kh[64][65];
  __shared__ float Vh[49][65];
  __shared__ float G[2401];
  int tid = threadIdx.x;
  for (int i = tid; i < 49 * 64; i += 256) {
    int k = i >> 6, d = i & 63;
    size_t off = (((size_t)(b * 49 + k)) << 9) + h * 64 + d;
    Kh[k][d] = kb[off];
    Vh[k][d] = vb[off];
  }
  for (int i = tid; i < 15 * 64; i += 256) {
    Kh[49 + (i >> 6)][i & 63] = 0.f;
  }
  for (int i = tid; i < 2401; i += 256) G[i] = gfac[b * 2401 + i];
  __syncthreads();
  int wave = tid >> 6, lane = tid & 63;
  for (int q = wave; q < 49; q += 4) {
    float qv = qb[(((size_t)(b * 49 + q)) << 9) + h * 64 + lane];
    float dot = 0.f;
#pragma unroll
    for (int d = 0; d < 64; d++) dot += __shfl(qv, d, 64) * Kh[lane][d];
    float enh = (lane < 49) ? dot * SCALEC * G[q * 49 + lane] : -1e30f;
    float mxv = wmax(enh);
    float e = (lane < 49) ? __expf(enh - mxv) : 0.f;
    float ssum = wsum(e);
    float w = e / ssum;
    float out = 0.f;
#pragma unroll
    for (int k = 0; k < 49; k++) out += __shfl(w, k, 64) * Vh[k][lane];
    aoh[(((size_t)(b * 49 + q)) << 9) + h * 64 + lane] = (f16)out;
  }
}

// ---------- launch ----------
extern "C" void kernel_launch(void* const* d_in, const int* in_sizes, int n_in,
                              void* d_out, int out_size, void* d_ws, size_t ws_size,
                              hipStream_t stream) {
  const float* queries = (const float*)d_in[0];
  const float* keys = (const float*)d_in[1];
  const float* values = (const float*)d_in[2];
  const float* Wq = (const float*)d_in[3];
  const float* bq = (const float*)d_in[4];
  const float* Wk = (const float*)d_in[5];
  const float* bk = (const float*)d_in[6];
  const float* Wv = (const float*)d_in[7];
  const float* bv = (const float*)d_in[8];
  const float* Wo = (const float*)d_in[9];
  const float* bo = (const float*)d_in[10];
  const float* rel_embed = (const float*)d_in[11];
  const float* Wproj = (const float*)d_in[12];
  const float* bproj = (const float*)d_in[13];
  const float* Wgate = (const float*)d_in[14];
  const float* bgate = (const float*)d_in[15];
  const float* Wc1 = (const float*)d_in[16];
  const float* bc1 = (const float*)d_in[17];
  const float* gc = (const float*)d_in[18];
  const float* bcln = (const float*)d_in[19];
  const float* Wc2 = (const float*)d_in[20];
  const float* bc2 = (const float*)d_in[21];
  const float* Wr1 = (const float*)d_in[22];
  const float* br1 = (const float*)d_in[23];
  const float* gr = (const float*)d_in[24];
  const float* brln = (const float*)d_in[25];
  const float* Wr2 = (const float*)d_in[26];
  const float* br2 = (const float*)d_in[27];
  const float* convW = (const float*)d_in[28];
  // d_in[29] = convb: cancelled by BatchNorm(affine=False)

  float* W = (float*)d_ws;
  size_t o = 0;
  f16* Qp = (f16*)(W + o); o += 663552;
  f16* Wtb = (f16*)(W + o); o += 1179648;
  f16* WqT = (f16*)(W + o); o += 131072;
  f16* WkT = (f16*)(W + o); o += 131072;
  f16* WvT = (f16*)(W + o); o += 131072;
  f16* WoT = (f16*)(W + o); o += 131072;
  f16* Wc1aT = (f16*)(W + o); o += 65536;
  f16* Wc1bT = (f16*)(W + o); o += 65536;
  f16* Wr1aT = (f16*)(W + o); o += 131072;
  f16* Wr1bT = (f16*)(W + o); o += 131072;
  float* hbuf = W + o; o += 802816;
  f16* eqh = (f16*)(W + o); o += 401408;
  f16* ekh = (f16*)(W + o); o += 401408;
  f16* evh = (f16*)(W + o); o += 401408;
  float* qbuf = W + o; o += 802816;
  float* kbuf = W + o; o += 802816;
  float* vbuf = W + o; o += 802816;
  float* Cqw = W + o; o += 401408;
  float* Ckw = W + o; o += 401408;
  float* Rqw = W + o; o += 802816;
  float* Rkw = W + o; o += 802816;
  f16* aoh = (f16*)(W + o); o += 200704;
  float* gf = W + o; o += 76832;
  float* mu = W + o; o += 512;
  float* rsg = W + o; o += 512;
  float* crel = W + o; o += 16;
  float* wrg = W + o; o += 512;
  float* ccst = W + o; o += 16;
  unsigned* CqT2 = (unsigned*)(W + o); o += 200704;  // [128][1568]
  unsigned* CkT2 = (unsigned*)(W + o); o += 200704;
  unsigned* RqT2 = (unsigned*)(W + o); o += 401408;  // [256][1568]
  unsigned* RkT2 = (unsigned*)(W + o); o += 401408;
  f16* Cqh = (f16*)(W + o); o += 200704;             // [1568][256] f16
  f16* Ckh = (f16*)(W + o); o += 200704;
  f16* Rqh = (f16*)(W + o); o += 401408;             // [1568][512] f16
  f16* Rkh = (f16*)(W + o); o += 401408;
  float* Ssum = W + o; o += 6272;                    // [4][1568]
  float* SSsum = W + o; o += 6272;
  float* dotC = W + o; o += 76832;
  float* dotR = W + o; o += 76832;

  SetupW tw;
  tw.src[0] = Wq;  tw.dst[0] = WqT;  tw.cols[0] = 512;
  tw.src[1] = Wk;  tw.dst[1] = WkT;  tw.cols[1] = 512;
  tw.src[2] = Wv;  tw.dst[2] = WvT;  tw.cols[2] = 512;
  tw.src[3] = Wo;  tw.dst[3] = WoT;  tw.cols[3] = 512;
  tw.src[4] = Wc1;             tw.dst[4] = Wc1aT; tw.cols[4] = 256;
  tw.src[5] = Wc1 + 512 * 256; tw.dst[5] = Wc1bT; tw.cols[5] = 256;
  tw.src[6] = Wr1;             tw.dst[6] = Wr1aT; tw.cols[6] = 512;
  tw.src[7] = Wr1 + 512 * 512; tw.dst[7] = Wr1bT; tw.cols[7] = 512;
  hipLaunchKernelGGL(setup, dim3(8913), dim3(256), 0, stream, queries, convW,
                     Wproj, Wgate, rel_embed, bproj, br2, bgate, Wr2, tw, hbuf,
                     Qp, Wtb, crel, wrg, ccst);

  hipLaunchKernelGGL(conv_mfma, dim3(8, 25, 4), dim3(256), 0, stream, Qp, Wtb, hbuf);
  hipLaunchKernelGGL(bn_stats, dim3(512), dim3(256), 0, stream, hbuf, mu, rsg);
  hipLaunchKernelGGL(fuse_xs, dim3(3136), dim3(256), 0, stream, hbuf, mu, rsg,
                     queries, keys, values, eqh, ekh, evh);

  MJobs jb;
  for (int z = 0; z < 7; z++) jb.Ch[z] = nullptr;
  jb.A[0] = eqh; jb.BT[0] = WqT;   jb.bias[0] = bq;      jb.C[0] = qbuf; jb.N[0] = 512;
  jb.A[1] = ekh; jb.BT[1] = WkT;   jb.bias[1] = bk;      jb.C[1] = kbuf; jb.N[1] = 512;
  jb.A[2] = evh; jb.BT[2] = WvT;   jb.bias[2] = bv;      jb.C[2] = vbuf; jb.N[2] = 512;
  jb.A[3] = eqh; jb.BT[3] = Wc1aT; jb.bias[3] = bc1;     jb.C[3] = Cqw;  jb.N[3] = 256; jb.Ch[3] = Cqh;
  jb.A[4] = ekh; jb.BT[4] = Wc1bT; jb.bias[4] = nullptr; jb.C[4] = Ckw;  jb.N[4] = 256; jb.Ch[4] = Ckh;
  jb.A[5] = eqh; jb.BT[5] = Wr1aT; jb.bias[5] = br1;     jb.C[5] = Rqw;  jb.N[5] = 512; jb.Ch[5] = Rqh;
  jb.A[6] = ekh; jb.BT[6] = Wr1bT; jb.bias[6] = nullptr; jb.C[6] = Rkw;  jb.N[6] = 512; jb.Ch[6] = Rkh;
  hipLaunchKernelGGL(gemm_mf, dim3(8, 25, 7), dim3(256), 0, stream, jb);

  MidA ma;
  ma.rs_src[0] = Cqw; ma.rs_w[0] = 256;
  ma.rs_src[1] = Ckw; ma.rs_w[1] = 256;
  ma.rs_src[2] = Rqw; ma.rs_w[2] = 512;
  ma.rs_src[3] = Rkw; ma.rs_w[3] = 512;
  ma.t2_src[0] = Cqw; ma.t2_dst[0] = CqT2; ma.t2_C[0] = 256;
  ma.t2_src[1] = Ckw; ma.t2_dst[1] = CkT2; ma.t2_C[1] = 256;
  ma.t2_src[2] = Rqw; ma.t2_dst[2] = RqT2; ma.t2_C[2] = 512;
  ma.t2_src[3] = Rkw; ma.t2_dst[3] = RkT2; ma.t2_C[3] = 512;
  ma.gA[0] = Cqh; ma.gB[0] = Ckh; ma.gOut[0] = dotC; ma.gK[0] = 256;
  ma.gA[1] = Rqh; ma.gB[1] = Rkh; ma.gOut[1] = dotR; ma.gK[1] = 512;
  hipLaunchKernelGGL(mid, dim3(3984), dim3(256), 0, stream, ma, Ssum, SSsum);

  hipLaunchKernelGGL(pair_gate, dim3((NPAIR * 4 + 255) / 256), dim3(256), 0, stream,
                     CqT2, CkT2, RqT2, RkT2, Wc2, bc2, gc, bcln, gr, brln, crel,
                     wrg, ccst, Ssum, SSsum, dotC, dotR, gf);
  hipLaunchKernelGGL(attn, dim3(256), dim3(256), 0, stream, qbuf, kbuf, vbuf, gf, aoh);

  MJobs j2;
  for (int z = 0; z < 7; z++) {
    j2.A[z] = nullptr; j2.BT[z] = nullptr; j2.bias[z] = nullptr;
    j2.C[z] = nullptr; j2.Ch[z] = nullptr; j2.N[z] = 0;
  }
  j2.A[0] = aoh; j2.BT[0] = WoT; j2.bias[0] = bo; j2.C[0] = (float*)d_out; j2.N[0] = 512;
  hipLaunchKernelGGL(gemm_mf, dim3(8, 25, 1), dim3(256), 0, stream, j2);
}